// Round 5
// baseline (861.479 us; speedup 1.0000x reference)
//
#include <hip/hip_runtime.h>
#include <math.h>

typedef __bf16 bf16;
typedef __bf16 bf16x8 __attribute__((ext_vector_type(8)));
typedef float  f32x4  __attribute__((ext_vector_type(4)));

// Problem constants
constexpr int B_   = 32;
constexpr int T_   = 256;
constexpr int V_   = 25;
constexpr int NTV  = T_ * V_;                 // 6400
constexpr long long TENSOR = (long long)B_ * 128 * NTV; // 26,214,400 elems

// ws layout (float slots).
// Aliased region [0, TENSOR): xgt (bf16) + conv weights + wgr4 during phase 1;
// fuse_mfma overwrites it with fp32 acc (all prior tenants dead by then).
constexpr long long ACC_OFF  = 0;                        // fp32 [32][6400][128]
constexpr long long XGT_OFF  = 0;                        // bf16 [32][6400][128]
constexpr long long WRB3_OFF = XGT_OFF + TENSOR / 2;     // bf16 conv weights
constexpr long long WRB5_OFF = WRB3_OFF + 128 * 128 * 3 / 2;
constexpr long long WRB7_OFF = WRB5_OFF + 128 * 128 * 5 / 2;
constexpr long long WGR_OFF  = WRB7_OFF + 128 * 128 * 7 / 2;  // fp32 8192 (wgr4)
// Non-aliased tail:
constexpr long long Y0_OFF   = ACC_OFF + TENSOR;         // bf16 x3 [32][6400][128]
constexpr long long Y1_OFF   = Y0_OFF + TENSOR / 2;
constexpr long long Y2_OFF   = Y1_OFF + TENSOR / 2;
constexpr long long XT_OFF   = Y2_OFF + TENSOR / 2;      // bf16 [32][6400][64]
constexpr long long ABIG_OFF = XT_OFF + TENSOR / 4;      // bf16 [32][128][448]
constexpr long long BIAS_OFF = ABIG_OFF + (32LL * 128 * 448) / 2; // f32 [32][128]
constexpr long long STATS_OFF = BIAS_OFF + 4096;         // 5 x 512 floats

__device__ __forceinline__ float bflo(unsigned u) { return __builtin_bit_cast(float, u << 16); }
__device__ __forceinline__ float bfhi(unsigned u) { return __builtin_bit_cast(float, u & 0xffff0000u); }
__device__ __forceinline__ unsigned packbf2(float a, float b) {
    unsigned short ua = __builtin_bit_cast(unsigned short, (bf16)a);
    unsigned short ub = __builtin_bit_cast(unsigned short, (bf16)b);
    return (unsigned)ua | ((unsigned)ub << 16);
}

// ---------------- combined prep: conv-w repack (bf16) + wgr4 pack + stats zero ----------------
constexpr int N3 = 128 * 128 * 3;   // 49152
constexpr int N5 = 128 * 128 * 5;   // 81920
constexpr int N7 = 128 * 128 * 7;   // 114688
constexpr int NW = N3 + N5 + N7;    // 245760
constexpr int PREP_TOT = NW + 8192 + 2560;   // 256512

__global__ void prep_kernel(const float* __restrict__ w3, const float* __restrict__ w5,
                            const float* __restrict__ w7, const float* __restrict__ wg,
                            bf16* __restrict__ wr3, bf16* __restrict__ wr5, bf16* __restrict__ wr7,
                            float* __restrict__ wgr4, float* __restrict__ stats) {
    int idx = blockIdx.x * 256 + threadIdx.x;
    if (idx < NW) {
        const float* w; bf16* wr; int K; int i = idx;
        if (i < N3)           { w = w3; wr = wr3; K = 3; }
        else if (i < N3 + N5) { i -= N3; w = w5; wr = wr5; K = 5; }
        else                  { i -= N3 + N5; w = w7; wr = wr7; K = 7; }
        int co = i / (128 * K);
        int rem = i - co * 128 * K;
        int ci = rem / K;
        int dt = rem - ci * K;
        wr[(co * K + dt) * 128 + ci] = (bf16)w[i];
    } else if (idx < NW + 8192) {
        int o = idx - NW;
        int h = o >> 11, c = (o >> 5) & 63, d = o & 31;
        wgr4[(((c >> 2) * 128) + h * 32 + d) * 4 + (c & 3)] = wg[o];
    } else if (idx < PREP_TOT) {
        stats[idx - (NW + 8192)] = 0.f;
    }
}

// ---------------- GAT: one (b,t) per block -> xgt [b][n][128], xt, gn1-stat partials ----------------
__global__ __launch_bounds__(256) void gat_kernel(const float* __restrict__ x,
                                                  const float* __restrict__ adj,
                                                  const float* __restrict__ wgr4,
                                                  const float* __restrict__ ag,
                                                  bf16* __restrict__ xgt,
                                                  bf16* __restrict__ xt,
                                                  float* __restrict__ raw1) {
    __shared__ float s_x[26 * 68];      // [v][c], stride 68 (16B-aligned rows); row 25 = overread slack
    __shared__ float s_wh[25 * 129];    // [v][hd], stride 129 (bank-spread for scalar phases)
    __shared__ float s_att[101 * 28];   // [h*25+i][j], stride 28, cols 25..27 zero; row 100 slack
    __shared__ float s_e1[100], s_e2[100];
    __shared__ float s_adj[625];
    __shared__ float s_rs[256], s_rq[256];

    int n = blockIdx.x;
    int b = n >> 8, t = n & 255;
    int tid = threadIdx.x;

    const float* xb = x + (long long)b * 64 * NTV + t * 25;
    for (int o = tid; o < 1600; o += 256) {
        int c = o / 25, v = o - c * 25;
        s_x[v * 68 + c] = xb[c * NTV + v];
    }
    for (int o = tid; o < 625; o += 256) s_adj[o] = adj[o];
    __syncthreads();

    // xt = bf16 transpose of this x slice (read-read with Wh phase, no sync needed)
    for (int o = tid; o < 1600; o += 256) {
        int v = o >> 6, c = o & 63;
        xt[((long long)(b * NTV + t * 25 + v)) * 64 + c] = (bf16)s_x[v * 68 + c];
    }

    int hd = tid & 127, vh = tid >> 7;
    int v0 = vh * 13, nv = vh ? 12 : 13;

    // preload W fragments: w4[c4] = wg[h][c4*4..c4*4+3][d] for this hd (coalesced float4)
    float4 w4[16];
    const float4* wp = (const float4*)wgr4;
#pragma unroll
    for (int c4 = 0; c4 < 16; ++c4) w4[c4] = wp[c4 * 128 + hd];

    float acc[13];
#pragma unroll
    for (int i = 0; i < 13; i++) acc[i] = 0.f;
    for (int c4 = 0; c4 < 16; ++c4) {
        float4 wv = w4[c4];
#pragma unroll
        for (int i = 0; i < 13; i++) {
            float4 xv = *reinterpret_cast<const float4*>(&s_x[(v0 + i) * 68 + c4 * 4]);
            acc[i] += xv.x * wv.x + xv.y * wv.y + xv.z * wv.z + xv.w * wv.w;
        }
    }
    for (int i = 0; i < nv; i++) s_wh[(v0 + i) * 129 + hd] = acc[i];
    __syncthreads();

    // e1/e2
    if (tid < 200) {
        int which = tid / 100;
        int r = tid - which * 100;
        int h = r / 25, i = r - h * 25;
        const float* a = ag + h * 64 + which * 32;
        float s = 0.f;
#pragma unroll
        for (int d = 0; d < 32; d++) s += s_wh[i * 129 + h * 32 + d] * a[d];
        if (which) s_e2[r] = s; else s_e1[r] = s;
    }
    __syncthreads();

    // masked softmax rows -> s_att (stride 28, zero-padded)
    if (tid < 100) {
        int h = tid / 25, i = tid - h * 25;
        float ei = s_e1[h * 25 + i];
        float ev[25];
        float mx = -3.4e38f;
#pragma unroll
        for (int j = 0; j < 25; j++) {
            float e = ei + s_e2[h * 25 + j];
            e = e > 0.f ? e : 0.2f * e;
            e = (s_adj[i * 25 + j] > 0.f) ? e : -9.0e15f;
            ev[j] = e;
            mx = fmaxf(mx, e);
        }
        float sum = 0.f;
#pragma unroll
        for (int j = 0; j < 25; j++) { float p = __expf(ev[j] - mx); ev[j] = p; sum += p; }
        float inv = 1.f / sum;
        int row = (h * 25 + i) * 28;
#pragma unroll
        for (int j = 0; j < 25; j++) s_att[row + j] = ev[j] * inv;
        s_att[row + 25] = 0.f; s_att[row + 26] = 0.f; s_att[row + 27] = 0.f;
    }
    __syncthreads();

    // PV: hp[v][hd] = sum_j att[h][v][j] * Wh[j][hd]
    int h = hd >> 5;
    float whr[28];
#pragma unroll
    for (int j = 0; j < 25; ++j) whr[j] = s_wh[j * 129 + hd];
    whr[25] = 0.f; whr[26] = 0.f; whr[27] = 0.f;
#pragma unroll
    for (int i = 0; i < 13; i++) acc[i] = 0.f;
#pragma unroll
    for (int i = 0; i < 13; i++) {
        int row = (h * 25 + v0 + i) * 28;
#pragma unroll
        for (int j4 = 0; j4 < 7; ++j4) {
            float4 a4 = *reinterpret_cast<const float4*>(&s_att[row + j4 * 4]);
            acc[i] += a4.x * whr[j4 * 4] + a4.y * whr[j4 * 4 + 1]
                    + a4.z * whr[j4 * 4 + 2] + a4.w * whr[j4 * 4 + 3];
        }
    }

    // epilogue: elu -> bf16 -> xgt; accumulate gn1-stat partials on rounded values
    float ssum = 0.f, qsum = 0.f;
    for (int i = 0; i < nv; i++) {
        float val = acc[i];
        val = val > 0.f ? val : expm1f(val);
        bf16 bv = (bf16)val;
        xgt[((long long)(b * NTV + t * 25 + v0 + i)) * 128 + hd] = bv;
        float f = (float)bv;
        ssum += f; qsum += f * f;
    }
    s_rs[tid] = ssum; s_rq[tid] = qsum;
    __syncthreads();
    if (tid < 8) {
        float ss = 0.f, qq = 0.f;
#pragma unroll
        for (int k = 0; k < 16; ++k) {
            int ch = tid * 16 + k;
            ss += s_rs[ch] + s_rs[ch + 128];
            qq += s_rq[ch] + s_rq[ch + 128];
        }
        atomicAdd(&raw1[b * 8 + tid], ss);
        atomicAdd(&raw1[256 + b * 8 + tid], qq);
    }
}

// ---------------- conv as MFMA GEMM (gn1+relu fused at staging; gn2-stat partials fused) ----------------
template <int K>
__global__ __launch_bounds__(256) void conv_mfma_kernel(const bf16* __restrict__ xgt,
                                                        const bf16* __restrict__ wr,
                                                        const float* __restrict__ bb,
                                                        const float* __restrict__ g1,
                                                        const float* __restrict__ b1,
                                                        const float* __restrict__ raw1,
                                                        bf16* __restrict__ y,
                                                        float* __restrict__ raw2) {
    constexpr int P = (K - 1) / 2;
    constexpr int ROWS = 128 + (K - 1) * 25;
    constexpr int NCH = ROWS * 16;
    constexpr int ITERS = (NCH + 255) / 256;
    __shared__ bf16 s_h[ROWS * 128];   // reused as s_y (128*136 <= ROWS*128 for K>=3)
    __shared__ float s_sc[128], s_bc[128];

    int tile = blockIdx.x, b = blockIdx.y, tid = threadIdx.x;
    int n0 = tile * 128;
    if (tid < 128) {
        int g = tid >> 4;
        float mu = raw1[b * 8 + g] * (1.f / 102400.f);
        float var = raw1[256 + b * 8 + g] * (1.f / 102400.f) - mu * mu;
        float rs = rsqrtf(var + 1e-5f);
        float sc = rs * g1[tid];
        s_sc[tid] = sc;
        s_bc[tid] = b1[tid] - mu * sc;
    }
    __syncthreads();

    int ch = tid & 15;
    float sc8[8], bc8[8];
#pragma unroll
    for (int j = 0; j < 8; ++j) { sc8[j] = s_sc[ch * 8 + j]; bc8[j] = s_bc[ch * 8 + j]; }

    int nb = b * NTV;
    for (int it = 0; it < ITERS; ++it) {
        int flat = it * 256 + tid;
        if (flat < NCH) {
            int r = flat >> 4;
            int n = n0 - P * 25 + r;
            uint4 v = {0u, 0u, 0u, 0u};
            if ((unsigned)n < (unsigned)NTV)
                v = *reinterpret_cast<const uint4*>(xgt + ((long long)(nb + n)) * 128 + ch * 8);
            unsigned w[4] = {v.x, v.y, v.z, v.w};
            uint4 o;
            unsigned* op = &o.x;
#pragma unroll
            for (int p = 0; p < 4; ++p) {
                float f0 = fmaxf(bflo(w[p]) * sc8[2 * p] + bc8[2 * p], 0.f);
                float f1 = fmaxf(bfhi(w[p]) * sc8[2 * p + 1] + bc8[2 * p + 1], 0.f);
                op[p] = packbf2(f0, f1);
            }
            *reinterpret_cast<uint4*>(s_h + r * 128 + (ch ^ (r & 15)) * 8) = o;
        }
    }
    __syncthreads();

    int wid = tid >> 6, lane = tid & 63, l15 = lane & 15, l4 = lane >> 4;
    int co0 = wid * 32;
    f32x4 acc[2][8];
#pragma unroll
    for (int m = 0; m < 2; ++m)
#pragma unroll
        for (int ns = 0; ns < 8; ++ns) acc[m][ns] = f32x4{0.f, 0.f, 0.f, 0.f};

    for (int dt = 0; dt < K; ++dt) {
#pragma unroll
        for (int cb = 0; cb < 4; ++cb) {
            const bf16* ap = wr + ((co0 + l15) * K + dt) * 128 + cb * 32 + l4 * 8;
            bf16x8 a0 = *(const bf16x8*)ap;
            bf16x8 a1 = *(const bf16x8*)(ap + 16 * K * 128);
#pragma unroll
            for (int ns = 0; ns < 8; ++ns) {
                int r = ns * 16 + l15 + dt * 25;
                int chunk = (cb * 4 + l4) ^ (r & 15);
                bf16x8 bv = *(const bf16x8*)(s_h + r * 128 + chunk * 8);
                acc[0][ns] = __builtin_amdgcn_mfma_f32_16x16x32_bf16(a0, bv, acc[0][ns], 0, 0, 0);
                acc[1][ns] = __builtin_amdgcn_mfma_f32_16x16x32_bf16(a1, bv, acc[1][ns], 0, 0, 0);
            }
        }
    }
    __syncthreads();   // s_h -> s_y reuse

    bf16* sy = s_h;
    float bias[2][4];
#pragma unroll
    for (int m = 0; m < 2; ++m)
#pragma unroll
        for (int rr = 0; rr < 4; ++rr) bias[m][rr] = bb[co0 + m * 16 + l4 * 4 + rr];
    float ssum[2] = {0.f, 0.f}, qsum[2] = {0.f, 0.f};
#pragma unroll
    for (int m = 0; m < 2; ++m)
#pragma unroll
        for (int ns = 0; ns < 8; ++ns) {
            int nl = ns * 16 + l15;
            uint2 pk;
            pk.x = packbf2(acc[m][ns][0] + bias[m][0], acc[m][ns][1] + bias[m][1]);
            pk.y = packbf2(acc[m][ns][2] + bias[m][2], acc[m][ns][3] + bias[m][3]);
            float f0 = bflo(pk.x), f1 = bfhi(pk.x), f2 = bflo(pk.y), f3 = bfhi(pk.y);
            ssum[m] += f0 + f1 + f2 + f3;
            qsum[m] += f0 * f0 + f1 * f1 + f2 * f2 + f3 * f3;
            *reinterpret_cast<uint2*>(sy + nl * 136 + co0 + m * 16 + l4 * 4) = pk;
        }
    // gn2-stat partials (on stored bf16 values): wave-reduce, group = wid*2+m
#pragma unroll
    for (int m = 0; m < 2; ++m) {
        float s = ssum[m], q = qsum[m];
#pragma unroll
        for (int off = 32; off > 0; off >>= 1) { s += __shfl_xor(s, off); q += __shfl_xor(q, off); }
        if (lane == 0) {
            atomicAdd(&raw2[b * 8 + wid * 2 + m], s);
            atomicAdd(&raw2[256 + b * 8 + wid * 2 + m], q);
        }
    }
    __syncthreads();
#pragma unroll
    for (int it = 0; it < 8; ++it) {
        int flat = it * 256 + tid;
        int nl = flat >> 4, c2 = flat & 15;
        uint4 v = *reinterpret_cast<const uint4*>(sy + nl * 136 + c2 * 8);
        *reinterpret_cast<uint4*>(y + ((long long)(nb + n0 + nl)) * 128 + c2 * 8) = v;
    }
}

// ---------------- fold gn2 into fusion weights (per batch), raw stats inlined ----------------
__global__ __launch_bounds__(256) void fold_kernel(const float* __restrict__ fus_w, const float* __restrict__ fus_b,
                                                   const float* __restrict__ res_w, const float* __restrict__ res_b,
                                                   const float* __restrict__ g20, const float* __restrict__ b20,
                                                   const float* __restrict__ g21, const float* __restrict__ b21,
                                                   const float* __restrict__ g22, const float* __restrict__ b22,
                                                   const float* __restrict__ st0, const float* __restrict__ st1,
                                                   const float* __restrict__ st2,
                                                   bf16* __restrict__ Abig, float* __restrict__ biasb) {
    __shared__ float s_sc[384], s_bc[384], s_part[256];
    int b = blockIdx.x, tid = threadIdx.x;
    for (int o = tid; o < 384; o += 256) {
        int k = o >> 7, cc = o & 127, g = cc >> 4;
        const float* st = (k == 0) ? st0 : (k == 1) ? st1 : st2;
        const float* gg = (k == 0) ? g20 : (k == 1) ? g21 : g22;
        const float* b2 = (k == 0) ? b20 : (k == 1) ? b21 : b22;
        float mu = st[b * 8 + g] * (1.f / 102400.f);
        float var = st[256 + b * 8 + g] * (1.f / 102400.f) - mu * mu;
        float rs = rsqrtf(var + 1e-5f);
        float sc = rs * gg[cc];
        s_sc[o] = sc;
        s_bc[o] = b2[cc] - mu * sc;
    }
    __syncthreads();
    for (int o = tid; o < 128 * 448; o += 256) {
        int co = o / 448, j = o - co * 448;
        float val = (j < 384) ? fus_w[co * 384 + j] * s_sc[j] : res_w[co * 64 + (j - 384)];
        Abig[((long long)(b * 128 + co)) * 448 + j] = (bf16)val;
    }
    int co = tid & 127, half = tid >> 7;
    float part = 0.f;
    for (int jj = 0; jj < 192; ++jj) {
        int j = half * 192 + jj;
        part += fus_w[co * 384 + j] * s_bc[j];
    }
    s_part[tid] = part;
    __syncthreads();
    if (half == 0)
        biasb[b * 128 + co] = fus_b[co] + res_b[co] + s_part[co] + s_part[128 + co];
}

// ---------------- fused output GEMM: acc(fp32) = Abig @ [y3|y5|y7|xt] + bias; gn3-stat partials ----------------
__global__ __launch_bounds__(256) void fuse_mfma_kernel(const bf16* __restrict__ y0, const bf16* __restrict__ y1,
                                                        const bf16* __restrict__ y2, const bf16* __restrict__ xt,
                                                        const bf16* __restrict__ Abig, const float* __restrict__ biasb,
                                                        float* __restrict__ accf, float* __restrict__ raw3) {
    __shared__ __align__(16) bf16 s_b[64 * 448];   // B operand; reused as fp32 out-stage after MFMA
    int tile = blockIdx.x, b = blockIdx.y, tid = threadIdx.x;
    int n0 = tile * 64;

    int c = tid % 56;
    int roff = tid / 56;
    bool act = tid < 224;
    const bf16* src;
    int stride;
    if (c < 48) {
        src = (c < 16 ? y0 : (c < 32 ? y1 : y2)) + (c & 15) * 8;
        stride = 128;
    } else {
        src = xt + (c - 48) * 8;
        stride = 64;
    }
    src += (long long)(b * NTV + n0) * stride;
    if (act) {
#pragma unroll
        for (int it = 0; it < 16; ++it) {
            int r = it * 4 + roff;
            uint4 v = *reinterpret_cast<const uint4*>(src + (long long)r * stride);
            *reinterpret_cast<uint4*>(s_b + r * 448 + (c ^ (r & 7)) * 8) = v;
        }
    }
    __syncthreads();

    int wid = tid >> 6, lane = tid & 63, l15 = lane & 15, l4 = lane >> 4;
    int co0 = wid * 32;
    f32x4 acc[2][4];
#pragma unroll
    for (int m = 0; m < 2; ++m)
#pragma unroll
        for (int ns = 0; ns < 4; ++ns) acc[m][ns] = f32x4{0.f, 0.f, 0.f, 0.f};

    const bf16* abase = Abig + ((long long)(b * 128 + co0 + l15)) * 448 + l4 * 8;
#pragma unroll
    for (int ks = 0; ks < 14; ++ks) {
        bf16x8 a0 = *(const bf16x8*)(abase + ks * 32);
        bf16x8 a1 = *(const bf16x8*)(abase + 16 * 448 + ks * 32);
        int ci = ks * 4 + l4;
#pragma unroll
        for (int ns = 0; ns < 4; ++ns) {
            int r = ns * 16 + l15;
            bf16x8 bv = *(const bf16x8*)(s_b + r * 448 + (ci ^ (r & 7)) * 8);
            acc[0][ns] = __builtin_amdgcn_mfma_f32_16x16x32_bf16(a0, bv, acc[0][ns], 0, 0, 0);
            acc[1][ns] = __builtin_amdgcn_mfma_f32_16x16x32_bf16(a1, bv, acc[1][ns], 0, 0, 0);
        }
    }

    float bias[2][4];
#pragma unroll
    for (int m = 0; m < 2; ++m)
#pragma unroll
        for (int rr = 0; rr < 4; ++rr) bias[m][rr] = biasb[b * 128 + co0 + m * 16 + l4 * 4 + rr];

    __syncthreads();   // all B reads complete; reuse s_b as fp32 staging
    float* s_yf = reinterpret_cast<float*>(s_b);   // [64][136] floats = 34.8 KB
    float ssum[2] = {0.f, 0.f}, qsum[2] = {0.f, 0.f};
#pragma unroll
    for (int m = 0; m < 2; ++m)
#pragma unroll
        for (int ns = 0; ns < 4; ++ns) {
            int nl = ns * 16 + l15;
            float4 val;
            val.x = acc[m][ns][0] + bias[m][0];
            val.y = acc[m][ns][1] + bias[m][1];
            val.z = acc[m][ns][2] + bias[m][2];
            val.w = acc[m][ns][3] + bias[m][3];
            float r0 = fmaxf(val.x, 0.f), r1 = fmaxf(val.y, 0.f);
            float r2 = fmaxf(val.z, 0.f), r3 = fmaxf(val.w, 0.f);
            ssum[m] += r0 + r1 + r2 + r3;
            qsum[m] += r0 * r0 + r1 * r1 + r2 * r2 + r3 * r3;
            *reinterpret_cast<float4*>(s_yf + nl * 136 + co0 + m * 16 + l4 * 4) = val;
        }
    // gn3-stat partials (relu of fp32 acc): wave-reduce, group = wid*2+m
#pragma unroll
    for (int m = 0; m < 2; ++m) {
        float s = ssum[m], q = qsum[m];
#pragma unroll
        for (int off = 32; off > 0; off >>= 1) { s += __shfl_xor(s, off); q += __shfl_xor(q, off); }
        if (lane == 0) {
            atomicAdd(&raw3[b * 8 + wid * 2 + m], s);
            atomicAdd(&raw3[256 + b * 8 + wid * 2 + m], q);
        }
    }
    __syncthreads();
#pragma unroll
    for (int it = 0; it < 8; ++it) {
        int flat = it * 256 + tid;
        int nl = flat >> 5, cq = flat & 31;
        float4 v = *reinterpret_cast<const float4*>(s_yf + nl * 136 + cq * 4);
        *reinterpret_cast<float4*>(accf + ((long long)(b * NTV + n0 + nl)) * 128 + cq * 4) = v;
    }
}

// ---------------- final: out = gn3(relu(acc fp32)), transpose to [b][c][n] fp32 ----------------
__global__ __launch_bounds__(256) void final_kernel(const float* __restrict__ accf,
                                                    const float* __restrict__ raw3,
                                                    const float* __restrict__ ng,
                                                    const float* __restrict__ nb,
                                                    float* __restrict__ out) {
    __shared__ float s_o[128 * 72];
    __shared__ float s_sc[128], s_bc[128];
    int tile = blockIdx.x, b = blockIdx.y, tid = threadIdx.x;
    int n0 = tile * 64;
    if (tid < 128) {
        int g = tid >> 4;
        float mu = raw3[b * 8 + g] * (1.f / 102400.f);
        float var = raw3[256 + b * 8 + g] * (1.f / 102400.f) - mu * mu;
        float rs = rsqrtf(var + 1e-5f);
        float sv = rs * ng[tid];
        s_sc[tid] = sv;
        s_bc[tid] = nb[tid] - mu * sv;
    }
    __syncthreads();
#pragma unroll
    for (int it = 0; it < 8; ++it) {
        int flat = it * 256 + tid;
        int r = flat >> 5, cq = flat & 31;
        float4 v = *reinterpret_cast<const float4*>(accf + ((long long)(b * NTV + n0 + r)) * 128 + cq * 4);
        float f[4] = {v.x, v.y, v.z, v.w};
#pragma unroll
        for (int p = 0; p < 4; ++p) {
            int ci = cq * 4 + p;
            s_o[ci * 72 + r] = fmaxf(f[p], 0.f) * s_sc[ci] + s_bc[ci];
        }
    }
    __syncthreads();
#pragma unroll
    for (int it = 0; it < 8; ++it) {
        int flat = it * 256 + tid;
        int ci = flat >> 4, q = flat & 15;
        float4 v = *reinterpret_cast<const float4*>(s_o + ci * 72 + q * 4);
        *reinterpret_cast<float4*>(out + ((long long)(b * 128 + ci)) * NTV + n0 + q * 4) = v;
    }
}

extern "C" void kernel_launch(void* const* d_in, const int* in_sizes, int n_in,
                              void* d_out, int out_size, void* d_ws, size_t ws_size,
                              hipStream_t stream) {
    const float* x      = (const float*)d_in[0];
    const float* adj    = (const float*)d_in[1];
    const float* w_gat  = (const float*)d_in[2];
    const float* a_gat  = (const float*)d_in[3];
    const float* fus_w  = (const float*)d_in[4];
    const float* fus_b  = (const float*)d_in[5];
    const float* res_w  = (const float*)d_in[6];
    const float* res_b  = (const float*)d_in[7];
    const float* norm_g = (const float*)d_in[8];
    const float* norm_b = (const float*)d_in[9];
    const float* tg1[3], *tb1[3], *tw[3], *tbb[3], *tg2[3], *tb2[3];
    for (int i = 0; i < 3; i++) {
        tg1[i] = (const float*)d_in[10 + 6 * i + 0];
        tb1[i] = (const float*)d_in[10 + 6 * i + 1];
        tw[i]  = (const float*)d_in[10 + 6 * i + 2];
        tbb[i] = (const float*)d_in[10 + 6 * i + 3];
        tg2[i] = (const float*)d_in[10 + 6 * i + 4];
        tb2[i] = (const float*)d_in[10 + 6 * i + 5];
    }

    float* ws = (float*)d_ws;
    float* accf  = ws + ACC_OFF;                    // fp32, aliases xgt/wrb/wgr4 (dead by fuse)
    bf16* xgt    = (bf16*)(ws + XGT_OFF);
    bf16* wrb[3] = { (bf16*)(ws + WRB3_OFF), (bf16*)(ws + WRB5_OFF), (bf16*)(ws + WRB7_OFF) };
    float* wgr4  = ws + WGR_OFF;
    bf16* yb[3]  = { (bf16*)(ws + Y0_OFF), (bf16*)(ws + Y1_OFF), (bf16*)(ws + Y2_OFF) };
    bf16* xt     = (bf16*)(ws + XT_OFF);
    bf16* Abig   = (bf16*)(ws + ABIG_OFF);
    float* biasb = ws + BIAS_OFF;
    float* S1    = ws + STATS_OFF;
    float* S2    = S1 + 512;      // 3 consecutive buffers (raw sums)
    float* S3    = S1 + 2048;

    prep_kernel<<<(PREP_TOT + 255) / 256, 256, 0, stream>>>(tw[0], tw[1], tw[2], w_gat,
                                                            wrb[0], wrb[1], wrb[2], wgr4, S1);

    gat_kernel<<<B_ * T_, 256, 0, stream>>>(x, adj, wgr4, a_gat, xgt, xt, S1);

    dim3 g64(100, 32), g128(50, 32);

    conv_mfma_kernel<3><<<g128, 256, 0, stream>>>(xgt, wrb[0], tbb[0], tg1[0], tb1[0], S1, yb[0], S2);
    conv_mfma_kernel<5><<<g128, 256, 0, stream>>>(xgt, wrb[1], tbb[1], tg1[1], tb1[1], S1, yb[1], S2 + 512);
    conv_mfma_kernel<7><<<g128, 256, 0, stream>>>(xgt, wrb[2], tbb[2], tg1[2], tb1[2], S1, yb[2], S2 + 1024);

    fold_kernel<<<32, 256, 0, stream>>>(fus_w, fus_b, res_w, res_b,
                                        tg2[0], tb2[0], tg2[1], tb2[1], tg2[2], tb2[2],
                                        S2, S2 + 512, S2 + 1024, Abig, biasb);

    // fuse overwrites the xgt/wrb/wgr4 region with fp32 acc (those are dead now)
    fuse_mfma_kernel<<<g64, 256, 0, stream>>>(yb[0], yb[1], yb[2], xt, Abig, biasb, accf, S3);

    final_kernel<<<g64, 256, 0, stream>>>(accf, S3, norm_g, norm_b, (float*)d_out);
}

// Round 6
// 656.981 us; speedup vs baseline: 1.3113x; 1.3113x over previous
//
#include <hip/hip_runtime.h>
#include <math.h>

typedef __bf16 bf16;
typedef __bf16 bf16x8 __attribute__((ext_vector_type(8)));
typedef float  f32x4  __attribute__((ext_vector_type(4)));

// Problem constants
constexpr int B_   = 32;
constexpr int T_   = 256;
constexpr int V_   = 25;
constexpr int NTV  = T_ * V_;                 // 6400
constexpr long long TENSOR = (long long)B_ * 128 * NTV; // 26,214,400 elems

// ws layout (float slots).
// Aliased region [0, TENSOR): xgt (bf16) + conv weights + wgb during phase 1;
// fuse_mfma overwrites it with fp32 acc (all prior tenants dead by then).
constexpr long long ACC_OFF  = 0;                        // fp32 [32][6400][128]
constexpr long long XGT_OFF  = 0;                        // bf16 [32][6400][128]
constexpr long long WRB3_OFF = XGT_OFF + TENSOR / 2;     // bf16 conv weights
constexpr long long WRB5_OFF = WRB3_OFF + 128 * 128 * 3 / 2;
constexpr long long WRB7_OFF = WRB5_OFF + 128 * 128 * 5 / 2;
constexpr long long WGB_OFF  = WRB7_OFF + 128 * 128 * 7 / 2;  // bf16 [128co][64ci]
// Non-aliased tail:
constexpr long long Y0_OFF   = ACC_OFF + TENSOR;         // bf16 x3 [32][6400][128]
constexpr long long Y1_OFF   = Y0_OFF + TENSOR / 2;
constexpr long long Y2_OFF   = Y1_OFF + TENSOR / 2;
constexpr long long XT_OFF   = Y2_OFF + TENSOR / 2;      // bf16 [32][6400][64]
constexpr long long ABIG_OFF = XT_OFF + TENSOR / 4;      // bf16 [32][128][448]
constexpr long long BIAS_OFF = ABIG_OFF + (32LL * 128 * 448) / 2; // f32 [32][128]
constexpr long long STATS_OFF = BIAS_OFF + 4096;         // 5 x 512 floats
// whbuf fp32 [204800][128] = TENSOR floats, aliases Y0+Y1 (dead before conv3 writes Y0)
constexpr long long WH_OFF   = Y0_OFF;

__device__ __forceinline__ float bflo(unsigned u) { return __builtin_bit_cast(float, u << 16); }
__device__ __forceinline__ float bfhi(unsigned u) { return __builtin_bit_cast(float, u & 0xffff0000u); }
__device__ __forceinline__ unsigned packbf2(float a, float b) {
    unsigned short ua = __builtin_bit_cast(unsigned short, (bf16)a);
    unsigned short ub = __builtin_bit_cast(unsigned short, (bf16)b);
    return (unsigned)ua | ((unsigned)ub << 16);
}

// ---------------- small prep kernels ----------------
__global__ void zero_stats_kernel(float* __restrict__ st) {
    int t = threadIdx.x;
    for (int o = t; o < 2560; o += 256) st[o] = 0.f;
}

// conv weight (co, ci, k) fp32 -> wr[co][dt][ci] bf16
__global__ void repack_wbf16_kernel(const float* __restrict__ w, bf16* __restrict__ wr, int K) {
    int idx = blockIdx.x * 256 + threadIdx.x;
    int tot = 128 * 128 * K;
    if (idx >= tot) return;
    int co  = idx / (128 * K);
    int rem = idx - co * 128 * K;
    int ci  = rem / K;
    int dt  = rem - ci * K;
    wr[(co * K + dt) * 128 + ci] = (bf16)w[idx];
}

// wg [h][c][d] fp32 -> wgb[(h*32+d)][c] bf16  (A-operand of Wh GEMM)
__global__ void repack_wgb_kernel(const float* __restrict__ wg, bf16* __restrict__ wgb) {
    int o = blockIdx.x * 256 + threadIdx.x;
    if (o >= 8192) return;
    int h = o >> 11, ci = (o >> 5) & 63, d = o & 31;
    wgb[(h * 32 + d) * 64 + ci] = (bf16)wg[o];
}

// x fp32 [b][64][n] -> xt bf16 [b][n][64]
__global__ __launch_bounds__(256) void xt_kernel(const float* __restrict__ x, bf16* __restrict__ xt) {
    __shared__ bf16 s_t[64 * 72];
    int tile = blockIdx.x, b = blockIdx.y, tid = threadIdx.x;
    int n0 = tile * 64;
#pragma unroll
    for (int it = 0; it < 4; ++it) {
        int flat = it * 256 + tid;
        int c = flat >> 4, q = flat & 15;
        float4 v = *reinterpret_cast<const float4*>(x + ((b * 64 + c) * NTV) + n0 + q * 4);
        s_t[(q * 4 + 0) * 72 + c] = (bf16)v.x;
        s_t[(q * 4 + 1) * 72 + c] = (bf16)v.y;
        s_t[(q * 4 + 2) * 72 + c] = (bf16)v.z;
        s_t[(q * 4 + 3) * 72 + c] = (bf16)v.w;
    }
    __syncthreads();
#pragma unroll
    for (int it = 0; it < 2; ++it) {
        int flat = it * 256 + tid;
        int nl = flat >> 3, c8 = flat & 7;
        uint4 v = *reinterpret_cast<const uint4*>(s_t + nl * 72 + c8 * 8);
        *reinterpret_cast<uint4*>(xt + ((long long)(b * NTV + n0 + nl)) * 64 + c8 * 8) = v;
    }
}

// ---------------- Wh GEMM: whbuf[n][128] fp32 = xt[n][64] @ wgb^T ----------------
__global__ __launch_bounds__(256) void wh_gemm_kernel(const bf16* __restrict__ xt,
                                                      const bf16* __restrict__ wgb,
                                                      float* __restrict__ whbuf) {
    __shared__ __align__(16) char s_raw[64 * 136 * 4];   // union: s_xt (8KB) then s_yf (34.8KB)
    bf16*  s_xt = reinterpret_cast<bf16*>(s_raw);
    float* s_yf = reinterpret_cast<float*>(s_raw);

    int tile = blockIdx.x, b = blockIdx.y, tid = threadIdx.x;
    long long nb0 = (long long)b * NTV + tile * 64;

    // stage 64 rows x 64 ci bf16, 16B-chunk XOR swizzle
#pragma unroll
    for (int it = 0; it < 2; ++it) {
        int flat = it * 256 + tid;
        int r = flat >> 3, ch = flat & 7;
        uint4 v = *reinterpret_cast<const uint4*>(xt + (nb0 + r) * 64 + ch * 8);
        *reinterpret_cast<uint4*>(s_xt + r * 64 + (ch ^ (r & 7)) * 8) = v;
    }
    __syncthreads();

    int wid = tid >> 6, lane = tid & 63, l15 = lane & 15, l4 = lane >> 4;
    int co0 = wid * 32;
    f32x4 acc[2][4];
#pragma unroll
    for (int m = 0; m < 2; ++m)
#pragma unroll
        for (int ns = 0; ns < 4; ++ns) acc[m][ns] = f32x4{0.f, 0.f, 0.f, 0.f};

#pragma unroll
    for (int cb = 0; cb < 2; ++cb) {
        const bf16* ap = wgb + (co0 + l15) * 64 + cb * 32 + l4 * 8;
        bf16x8 a0 = *(const bf16x8*)ap;
        bf16x8 a1 = *(const bf16x8*)(ap + 16 * 64);
#pragma unroll
        for (int ns = 0; ns < 4; ++ns) {
            int r = ns * 16 + l15;
            int chunk = (cb * 4 + l4) ^ (r & 7);
            bf16x8 bv = *(const bf16x8*)(s_xt + r * 64 + chunk * 8);
            acc[0][ns] = __builtin_amdgcn_mfma_f32_16x16x32_bf16(a0, bv, acc[0][ns], 0, 0, 0);
            acc[1][ns] = __builtin_amdgcn_mfma_f32_16x16x32_bf16(a1, bv, acc[1][ns], 0, 0, 0);
        }
    }
    __syncthreads();   // s_xt -> s_yf reuse

#pragma unroll
    for (int m = 0; m < 2; ++m)
#pragma unroll
        for (int ns = 0; ns < 4; ++ns) {
            int nl = ns * 16 + l15;
            float4 val;
            val.x = acc[m][ns][0]; val.y = acc[m][ns][1];
            val.z = acc[m][ns][2]; val.w = acc[m][ns][3];
            *reinterpret_cast<float4*>(s_yf + nl * 136 + co0 + m * 16 + l4 * 4) = val;
        }
    __syncthreads();
#pragma unroll
    for (int it = 0; it < 8; ++it) {
        int flat = it * 256 + tid;
        int nl = flat >> 5, cq = flat & 31;
        float4 v = *reinterpret_cast<const float4*>(s_yf + nl * 136 + cq * 4);
        *reinterpret_cast<float4*>(whbuf + (nb0 + nl) * 128 + cq * 4) = v;
    }
}

// ---------------- GAT attention: per (b,t), Wh precomputed -> xgt [b][n][128] ----------------
__global__ __launch_bounds__(256) void gat_att_kernel(const float* __restrict__ whbuf,
                                                      const float* __restrict__ adj,
                                                      const float* __restrict__ ag,
                                                      bf16* __restrict__ xgt) {
    __shared__ float s_wh[25 * 132];    // [v][hd], stride 132 (16B-aligned, bank-spread)
    __shared__ float s_att[101 * 28];   // [h*25+i][j], stride 28, cols 25..27 zero
    __shared__ float s_e1[100], s_e2[100];
    __shared__ float s_adj[625];

    int n = blockIdx.x;
    int b = n >> 8, t = n & 255;
    int tid = threadIdx.x;

    const float* src = whbuf + ((long long)(b * NTV + t * 25)) * 128;
    for (int o = tid; o < 800; o += 256) {
        int v = o >> 5, q = o & 31;
        float4 w = *reinterpret_cast<const float4*>(src + v * 128 + q * 4);
        *reinterpret_cast<float4*>(&s_wh[v * 132 + q * 4]) = w;
    }
    for (int o = tid; o < 625; o += 256) s_adj[o] = adj[o];
    __syncthreads();

    // e1/e2
    if (tid < 200) {
        int which = tid / 100;
        int r = tid - which * 100;
        int h = r / 25, i = r - h * 25;
        const float* a = ag + h * 64 + which * 32;
        float s = 0.f;
#pragma unroll
        for (int d = 0; d < 32; d++) s += s_wh[i * 132 + h * 32 + d] * a[d];
        if (which) s_e2[r] = s; else s_e1[r] = s;
    }
    __syncthreads();

    // masked softmax rows -> s_att (stride 28, zero-padded)
    if (tid < 100) {
        int h = tid / 25, i = tid - h * 25;
        float ei = s_e1[h * 25 + i];
        float ev[25];
        float mx = -3.4e38f;
#pragma unroll
        for (int j = 0; j < 25; j++) {
            float e = ei + s_e2[h * 25 + j];
            e = e > 0.f ? e : 0.2f * e;
            e = (s_adj[i * 25 + j] > 0.f) ? e : -9.0e15f;
            ev[j] = e;
            mx = fmaxf(mx, e);
        }
        float sum = 0.f;
#pragma unroll
        for (int j = 0; j < 25; j++) { float p = __expf(ev[j] - mx); ev[j] = p; sum += p; }
        float inv = 1.f / sum;
        int row = (h * 25 + i) * 28;
#pragma unroll
        for (int j = 0; j < 25; j++) s_att[row + j] = ev[j] * inv;
        s_att[row + 25] = 0.f; s_att[row + 26] = 0.f; s_att[row + 27] = 0.f;
    }
    __syncthreads();

    // PV: hp[v][hd] = sum_j att[h][v][j] * Wh[j][hd]
    int hd = tid & 127, vh = tid >> 7;
    int v0 = vh * 13, nv = vh ? 12 : 13;
    int h = hd >> 5;
    float whr[28];
#pragma unroll
    for (int j = 0; j < 25; ++j) whr[j] = s_wh[j * 132 + hd];
    whr[25] = 0.f; whr[26] = 0.f; whr[27] = 0.f;
    float acc[13];
#pragma unroll
    for (int i = 0; i < 13; i++) acc[i] = 0.f;
#pragma unroll
    for (int i = 0; i < 13; i++) {
        int row = (h * 25 + v0 + i) * 28;
#pragma unroll
        for (int j4 = 0; j4 < 7; ++j4) {
            float4 a4 = *reinterpret_cast<const float4*>(&s_att[row + j4 * 4]);
            acc[i] += a4.x * whr[j4 * 4] + a4.y * whr[j4 * 4 + 1]
                    + a4.z * whr[j4 * 4 + 2] + a4.w * whr[j4 * 4 + 3];
        }
    }

    // epilogue: elu -> bf16 -> xgt
    for (int i = 0; i < nv; i++) {
        float val = acc[i];
        val = val > 0.f ? val : expm1f(val);
        xgt[((long long)(b * NTV + t * 25 + v0 + i)) * 128 + hd] = (bf16)val;
    }
}

// ---------------- group stats on [b][n][128] bf16 ----------------
template <bool RELU>
__global__ __launch_bounds__(256) void stats_c128_kernel(const bf16* __restrict__ src, float* __restrict__ raw) {
    __shared__ float s_s[256], s_q[256];
    int b = blockIdx.x, sl = blockIdx.y, tid = threadIdx.x;
    int ch = tid & 15;
    const bf16* base = src + ((long long)(b * NTV + sl * 400 + (tid >> 4))) * 128 + ch * 8;
    float s = 0.f, q = 0.f;
    for (int it = 0; it < 25; ++it) {
        uint4 v = *reinterpret_cast<const uint4*>(base + (long long)it * 16 * 128);
        unsigned w[4] = {v.x, v.y, v.z, v.w};
#pragma unroll
        for (int p = 0; p < 4; ++p) {
            float f0 = bflo(w[p]), f1 = bfhi(w[p]);
            if (RELU) { f0 = fmaxf(f0, 0.f); f1 = fmaxf(f1, 0.f); }
            s += f0 + f1;
            q += f0 * f0 + f1 * f1;
        }
    }
    s_s[tid] = s; s_q[tid] = q;
    __syncthreads();
    if (tid < 8) {
        float ss = 0.f, qq = 0.f;
        for (int i = 0; i < 16; ++i) {
            int j = i * 16 + tid * 2;
            ss += s_s[j] + s_s[j + 1];
            qq += s_q[j] + s_q[j + 1];
        }
        atomicAdd(&raw[b * 8 + tid], ss);
        atomicAdd(&raw[256 + b * 8 + tid], qq);
    }
}

// group stats on [b][n][128] fp32 (with relu) — for the fused accumulator
__global__ __launch_bounds__(256) void stats_f32_relu_kernel(const float* __restrict__ src, float* __restrict__ raw) {
    __shared__ float s_s[256], s_q[256];
    int b = blockIdx.x, sl = blockIdx.y, tid = threadIdx.x;
    int cq = tid & 31;
    int r0 = sl * 400 + (tid >> 5);
    const float* base = src + ((long long)(b * NTV + r0)) * 128 + cq * 4;
    float s = 0.f, q = 0.f;
    for (int it = 0; it < 50; ++it) {
        float4 v = *reinterpret_cast<const float4*>(base + (long long)it * 8 * 128);
        float f0 = fmaxf(v.x, 0.f), f1 = fmaxf(v.y, 0.f);
        float f2 = fmaxf(v.z, 0.f), f3 = fmaxf(v.w, 0.f);
        s += f0 + f1 + f2 + f3;
        q += f0 * f0 + f1 * f1 + f2 * f2 + f3 * f3;
    }
    s_s[tid] = s; s_q[tid] = q;
    __syncthreads();
    if (tid < 8) {
        float ss = 0.f, qq = 0.f;
        for (int k = 0; k < 8; ++k)
            for (int j = 0; j < 4; ++j) {
                int t = k * 32 + tid * 4 + j;
                ss += s_s[t]; qq += s_q[t];
            }
        atomicAdd(&raw[b * 8 + tid], ss);
        atomicAdd(&raw[256 + b * 8 + tid], qq);
    }
}

__global__ void finalize_kernel(float* __restrict__ raw) {
    float* p = raw + blockIdx.x * 512;
    int t = threadIdx.x;
    float s = p[t], q = p[256 + t];
    float mu = s * (1.f / 102400.f);
    float var = q * (1.f / 102400.f) - mu * mu;
    p[t] = mu;
    p[256 + t] = rsqrtf(var + 1e-5f);
}

// ---------------- conv as MFMA GEMM (gn1+relu fused at staging) ----------------
template <int K>
__global__ __launch_bounds__(256) void conv_mfma_kernel(const bf16* __restrict__ xgt,
                                                        const bf16* __restrict__ wr,
                                                        const float* __restrict__ bb,
                                                        const float* __restrict__ g1,
                                                        const float* __restrict__ b1,
                                                        const float* __restrict__ stats1,
                                                        bf16* __restrict__ y) {
    constexpr int P = (K - 1) / 2;
    constexpr int ROWS = 128 + (K - 1) * 25;
    constexpr int NCH = ROWS * 16;
    constexpr int ITERS = (NCH + 255) / 256;
    __shared__ bf16 s_h[ROWS * 128];   // reused as s_y (128*136 <= ROWS*128 for K>=3)
    __shared__ float s_sc[128], s_bc[128];

    int tile = blockIdx.x, b = blockIdx.y, tid = threadIdx.x;
    int n0 = tile * 128;
    if (tid < 128) {
        int g = tid >> 4;
        float mu = stats1[b * 8 + g], rs = stats1[256 + b * 8 + g];
        float sc = rs * g1[tid];
        s_sc[tid] = sc;
        s_bc[tid] = b1[tid] - mu * sc;
    }
    __syncthreads();

    int ch = tid & 15;
    float sc8[8], bc8[8];
#pragma unroll
    for (int j = 0; j < 8; ++j) { sc8[j] = s_sc[ch * 8 + j]; bc8[j] = s_bc[ch * 8 + j]; }

    int nb = b * NTV;
    for (int it = 0; it < ITERS; ++it) {
        int flat = it * 256 + tid;
        if (flat < NCH) {
            int r = flat >> 4;
            int n = n0 - P * 25 + r;
            uint4 v = {0u, 0u, 0u, 0u};
            if ((unsigned)n < (unsigned)NTV)
                v = *reinterpret_cast<const uint4*>(xgt + ((long long)(nb + n)) * 128 + ch * 8);
            unsigned w[4] = {v.x, v.y, v.z, v.w};
            uint4 o;
            unsigned* op = &o.x;
#pragma unroll
            for (int p = 0; p < 4; ++p) {
                float f0 = fmaxf(bflo(w[p]) * sc8[2 * p] + bc8[2 * p], 0.f);
                float f1 = fmaxf(bfhi(w[p]) * sc8[2 * p + 1] + bc8[2 * p + 1], 0.f);
                op[p] = packbf2(f0, f1);
            }
            *reinterpret_cast<uint4*>(s_h + r * 128 + (ch ^ (r & 15)) * 8) = o;
        }
    }
    __syncthreads();

    int wid = tid >> 6, lane = tid & 63, l15 = lane & 15, l4 = lane >> 4;
    int co0 = wid * 32;
    f32x4 acc[2][8];
#pragma unroll
    for (int m = 0; m < 2; ++m)
#pragma unroll
        for (int ns = 0; ns < 8; ++ns) acc[m][ns] = f32x4{0.f, 0.f, 0.f, 0.f};

    for (int dt = 0; dt < K; ++dt) {
#pragma unroll
        for (int cb = 0; cb < 4; ++cb) {
            const bf16* ap = wr + ((co0 + l15) * K + dt) * 128 + cb * 32 + l4 * 8;
            bf16x8 a0 = *(const bf16x8*)ap;
            bf16x8 a1 = *(const bf16x8*)(ap + 16 * K * 128);
#pragma unroll
            for (int ns = 0; ns < 8; ++ns) {
                int r = ns * 16 + l15 + dt * 25;
                int chunk = (cb * 4 + l4) ^ (r & 15);
                bf16x8 bv = *(const bf16x8*)(s_h + r * 128 + chunk * 8);
                acc[0][ns] = __builtin_amdgcn_mfma_f32_16x16x32_bf16(a0, bv, acc[0][ns], 0, 0, 0);
                acc[1][ns] = __builtin_amdgcn_mfma_f32_16x16x32_bf16(a1, bv, acc[1][ns], 0, 0, 0);
            }
        }
    }
    __syncthreads();   // s_h -> s_y reuse

    bf16* sy = s_h;
    float bias[2][4];
#pragma unroll
    for (int m = 0; m < 2; ++m)
#pragma unroll
        for (int rr = 0; rr < 4; ++rr) bias[m][rr] = bb[co0 + m * 16 + l4 * 4 + rr];
#pragma unroll
    for (int m = 0; m < 2; ++m)
#pragma unroll
        for (int ns = 0; ns < 8; ++ns) {
            int nl = ns * 16 + l15;
            uint2 pk;
            pk.x = packbf2(acc[m][ns][0] + bias[m][0], acc[m][ns][1] + bias[m][1]);
            pk.y = packbf2(acc[m][ns][2] + bias[m][2], acc[m][ns][3] + bias[m][3]);
            *reinterpret_cast<uint2*>(sy + nl * 136 + co0 + m * 16 + l4 * 4) = pk;
        }
    __syncthreads();
#pragma unroll
    for (int it = 0; it < 8; ++it) {
        int flat = it * 256 + tid;
        int nl = flat >> 4, c2 = flat & 15;
        uint4 v = *reinterpret_cast<const uint4*>(sy + nl * 136 + c2 * 8);
        *reinterpret_cast<uint4*>(y + ((long long)(nb + n0 + nl)) * 128 + c2 * 8) = v;
    }
}

// ---------------- fold gn2 into fusion weights (per batch) ----------------
__global__ __launch_bounds__(256) void fold_kernel(const float* __restrict__ fus_w, const float* __restrict__ fus_b,
                                                   const float* __restrict__ res_w, const float* __restrict__ res_b,
                                                   const float* __restrict__ g20, const float* __restrict__ b20,
                                                   const float* __restrict__ g21, const float* __restrict__ b21,
                                                   const float* __restrict__ g22, const float* __restrict__ b22,
                                                   const float* __restrict__ st0, const float* __restrict__ st1,
                                                   const float* __restrict__ st2,
                                                   bf16* __restrict__ Abig, float* __restrict__ biasb) {
    __shared__ float s_sc[384], s_bc[384], s_part[256];
    int b = blockIdx.x, tid = threadIdx.x;
    for (int o = tid; o < 384; o += 256) {
        int k = o >> 7, cc = o & 127, g = cc >> 4;
        const float* st = (k == 0) ? st0 : (k == 1) ? st1 : st2;
        const float* gg = (k == 0) ? g20 : (k == 1) ? g21 : g22;
        const float* b2 = (k == 0) ? b20 : (k == 1) ? b21 : b22;
        float mu = st[b * 8 + g], rs = st[256 + b * 8 + g];
        float sc = rs * gg[cc];
        s_sc[o] = sc;
        s_bc[o] = b2[cc] - mu * sc;
    }
    __syncthreads();
    for (int o = tid; o < 128 * 448; o += 256) {
        int co = o / 448, j = o - co * 448;
        float val = (j < 384) ? fus_w[co * 384 + j] * s_sc[j] : res_w[co * 64 + (j - 384)];
        Abig[((long long)(b * 128 + co)) * 448 + j] = (bf16)val;
    }
    int co = tid & 127, half = tid >> 7;
    float part = 0.f;
    for (int jj = 0; jj < 192; ++jj) {
        int j = half * 192 + jj;
        part += fus_w[co * 384 + j] * s_bc[j];
    }
    s_part[tid] = part;
    __syncthreads();
    if (half == 0)
        biasb[b * 128 + co] = fus_b[co] + res_b[co] + s_part[co] + s_part[128 + co];
}

// ---------------- fused output GEMM: acc(fp32) = Abig @ [y3|y5|y7|xt] + bias ----------------
__global__ __launch_bounds__(256) void fuse_mfma_kernel(const bf16* __restrict__ y0, const bf16* __restrict__ y1,
                                                        const bf16* __restrict__ y2, const bf16* __restrict__ xt,
                                                        const bf16* __restrict__ Abig, const float* __restrict__ biasb,
                                                        float* __restrict__ accf) {
    __shared__ __align__(16) bf16 s_b[64 * 448];   // B operand; reused as fp32 out-stage after MFMA
    int tile = blockIdx.x, b = blockIdx.y, tid = threadIdx.x;
    int n0 = tile * 64;

    int c = tid % 56;
    int roff = tid / 56;
    bool act = tid < 224;
    const bf16* src;
    int stride;
    if (c < 48) {
        src = (c < 16 ? y0 : (c < 32 ? y1 : y2)) + (c & 15) * 8;
        stride = 128;
    } else {
        src = xt + (c - 48) * 8;
        stride = 64;
    }
    src += (long long)(b * NTV + n0) * stride;
    if (act) {
#pragma unroll
        for (int it = 0; it < 16; ++it) {
            int r = it * 4 + roff;
            uint4 v = *reinterpret_cast<const uint4*>(src + (long long)r * stride);
            *reinterpret_cast<uint4*>(s_b + r * 448 + (c ^ (r & 7)) * 8) = v;
        }
    }
    __syncthreads();

    int wid = tid >> 6, lane = tid & 63, l15 = lane & 15, l4 = lane >> 4;
    int co0 = wid * 32;
    f32x4 acc[2][4];
#pragma unroll
    for (int m = 0; m < 2; ++m)
#pragma unroll
        for (int ns = 0; ns < 4; ++ns) acc[m][ns] = f32x4{0.f, 0.f, 0.f, 0.f};

    const bf16* abase = Abig + ((long long)(b * 128 + co0 + l15)) * 448 + l4 * 8;
#pragma unroll
    for (int ks = 0; ks < 14; ++ks) {
        bf16x8 a0 = *(const bf16x8*)(abase + ks * 32);
        bf16x8 a1 = *(const bf16x8*)(abase + 16 * 448 + ks * 32);
        int ci = ks * 4 + l4;
#pragma unroll
        for (int ns = 0; ns < 4; ++ns) {
            int r = ns * 16 + l15;
            bf16x8 bv = *(const bf16x8*)(s_b + r * 448 + (ci ^ (r & 7)) * 8);
            acc[0][ns] = __builtin_amdgcn_mfma_f32_16x16x32_bf16(a0, bv, acc[0][ns], 0, 0, 0);
            acc[1][ns] = __builtin_amdgcn_mfma_f32_16x16x32_bf16(a1, bv, acc[1][ns], 0, 0, 0);
        }
    }

    float bias[2][4];
#pragma unroll
    for (int m = 0; m < 2; ++m)
#pragma unroll
        for (int rr = 0; rr < 4; ++rr) bias[m][rr] = biasb[b * 128 + co0 + m * 16 + l4 * 4 + rr];

    __syncthreads();   // all B reads complete; reuse s_b as fp32 staging
    float* s_yf = reinterpret_cast<float*>(s_b);   // [64][136] floats = 34.8 KB
#pragma unroll
    for (int m = 0; m < 2; ++m)
#pragma unroll
        for (int ns = 0; ns < 4; ++ns) {
            int nl = ns * 16 + l15;
            float4 val;
            val.x = acc[m][ns][0] + bias[m][0];
            val.y = acc[m][ns][1] + bias[m][1];
            val.z = acc[m][ns][2] + bias[m][2];
            val.w = acc[m][ns][3] + bias[m][3];
            *reinterpret_cast<float4*>(s_yf + nl * 136 + co0 + m * 16 + l4 * 4) = val;
        }
    __syncthreads();
#pragma unroll
    for (int it = 0; it < 8; ++it) {
        int flat = it * 256 + tid;
        int nl = flat >> 5, cq = flat & 31;
        float4 v = *reinterpret_cast<const float4*>(s_yf + nl * 136 + cq * 4);
        *reinterpret_cast<float4*>(accf + ((long long)(b * NTV + n0 + nl)) * 128 + cq * 4) = v;
    }
}

// ---------------- final: out = gn3(relu(acc fp32)), transpose to [b][c][n] fp32 ----------------
__global__ __launch_bounds__(256) void final_kernel(const float* __restrict__ accf,
                                                    const float* __restrict__ stats3,
                                                    const float* __restrict__ ng,
                                                    const float* __restrict__ nb,
                                                    float* __restrict__ out) {
    __shared__ float s_o[128 * 72];
    __shared__ float s_sc[128], s_bc[128];
    int tile = blockIdx.x, b = blockIdx.y, tid = threadIdx.x;
    int n0 = tile * 64;
    if (tid < 128) {
        int g = tid >> 4;
        float mu = stats3[b * 8 + g], rs = stats3[256 + b * 8 + g];
        float sv = rs * ng[tid];
        s_sc[tid] = sv;
        s_bc[tid] = nb[tid] - mu * sv;
    }
    __syncthreads();
#pragma unroll
    for (int it = 0; it < 8; ++it) {
        int flat = it * 256 + tid;
        int r = flat >> 5, cq = flat & 31;
        float4 v = *reinterpret_cast<const float4*>(accf + ((long long)(b * NTV + n0 + r)) * 128 + cq * 4);
        float f[4] = {v.x, v.y, v.z, v.w};
#pragma unroll
        for (int p = 0; p < 4; ++p) {
            int ci = cq * 4 + p;
            s_o[ci * 72 + r] = fmaxf(f[p], 0.f) * s_sc[ci] + s_bc[ci];
        }
    }
    __syncthreads();
#pragma unroll
    for (int it = 0; it < 8; ++it) {
        int flat = it * 256 + tid;
        int ci = flat >> 4, q = flat & 15;
        float4 v = *reinterpret_cast<const float4*>(s_o + ci * 72 + q * 4);
        *reinterpret_cast<float4*>(out + ((long long)(b * 128 + ci)) * NTV + n0 + q * 4) = v;
    }
}

extern "C" void kernel_launch(void* const* d_in, const int* in_sizes, int n_in,
                              void* d_out, int out_size, void* d_ws, size_t ws_size,
                              hipStream_t stream) {
    const float* x      = (const float*)d_in[0];
    const float* adj    = (const float*)d_in[1];
    const float* w_gat  = (const float*)d_in[2];
    const float* a_gat  = (const float*)d_in[3];
    const float* fus_w  = (const float*)d_in[4];
    const float* fus_b  = (const float*)d_in[5];
    const float* res_w  = (const float*)d_in[6];
    const float* res_b  = (const float*)d_in[7];
    const float* norm_g = (const float*)d_in[8];
    const float* norm_b = (const float*)d_in[9];
    const float* tg1[3], *tb1[3], *tw[3], *tbb[3], *tg2[3], *tb2[3];
    for (int i = 0; i < 3; i++) {
        tg1[i] = (const float*)d_in[10 + 6 * i + 0];
        tb1[i] = (const float*)d_in[10 + 6 * i + 1];
        tw[i]  = (const float*)d_in[10 + 6 * i + 2];
        tbb[i] = (const float*)d_in[10 + 6 * i + 3];
        tg2[i] = (const float*)d_in[10 + 6 * i + 4];
        tb2[i] = (const float*)d_in[10 + 6 * i + 5];
    }

    float* ws = (float*)d_ws;
    float* accf  = ws + ACC_OFF;                    // fp32, aliases xgt/wrb/wgb (dead by fuse)
    bf16* xgt    = (bf16*)(ws + XGT_OFF);
    bf16* wrb[3] = { (bf16*)(ws + WRB3_OFF), (bf16*)(ws + WRB5_OFF), (bf16*)(ws + WRB7_OFF) };
    bf16* wgb    = (bf16*)(ws + WGB_OFF);
    float* whbuf = ws + WH_OFF;                     // fp32, aliases Y0+Y1 (dead before conv3)
    bf16* yb[3]  = { (bf16*)(ws + Y0_OFF), (bf16*)(ws + Y1_OFF), (bf16*)(ws + Y2_OFF) };
    bf16* xt     = (bf16*)(ws + XT_OFF);
    bf16* Abig   = (bf16*)(ws + ABIG_OFF);
    float* biasb = ws + BIAS_OFF;
    float* S1    = ws + STATS_OFF;
    float* S2    = S1 + 512;      // 3 consecutive buffers
    float* S3    = S1 + 2048;

    const int Ks[3] = { 3, 5, 7 };

    zero_stats_kernel<<<1, 256, 0, stream>>>(S1);
    for (int i = 0; i < 3; i++) {
        int tot = 128 * 128 * Ks[i];
        repack_wbf16_kernel<<<(tot + 255) / 256, 256, 0, stream>>>(tw[i], wrb[i], Ks[i]);
    }
    repack_wgb_kernel<<<32, 256, 0, stream>>>(w_gat, wgb);

    dim3 g64(100, 32), g128(50, 32), gstat(32, 16);

    xt_kernel<<<g64, 256, 0, stream>>>(x, xt);

    // GAT = Wh GEMM (MFMA) + attention kernel
    wh_gemm_kernel<<<g64, 256, 0, stream>>>(xt, wgb, whbuf);
    gat_att_kernel<<<B_ * T_, 256, 0, stream>>>(whbuf, adj, a_gat, xgt);

    stats_c128_kernel<false><<<gstat, 256, 0, stream>>>(xgt, S1);
    finalize_kernel<<<1, 256, 0, stream>>>(S1);

    conv_mfma_kernel<3><<<g128, 256, 0, stream>>>(xgt, wrb[0], tbb[0], tg1[0], tb1[0], S1, yb[0]);
    conv_mfma_kernel<5><<<g128, 256, 0, stream>>>(xgt, wrb[1], tbb[1], tg1[1], tb1[1], S1, yb[1]);
    conv_mfma_kernel<7><<<g128, 256, 0, stream>>>(xgt, wrb[2], tbb[2], tg1[2], tb1[2], S1, yb[2]);

    stats_c128_kernel<false><<<gstat, 256, 0, stream>>>(yb[0], S2);
    stats_c128_kernel<false><<<gstat, 256, 0, stream>>>(yb[1], S2 + 512);
    stats_c128_kernel<false><<<gstat, 256, 0, stream>>>(yb[2], S2 + 1024);
    finalize_kernel<<<3, 256, 0, stream>>>(S2);

    fold_kernel<<<32, 256, 0, stream>>>(fus_w, fus_b, res_w, res_b,
                                        tg2[0], tb2[0], tg2[1], tb2[1], tg2[2], tb2[2],
                                        S2, S2 + 512, S2 + 1024, Abig, biasb);

    // fuse overwrites the xgt/wrb/wgb region with fp32 acc (those are dead now)
    fuse_mfma_kernel<<<g64, 256, 0, stream>>>(yb[0], yb[1], yb[2], xt, Abig, biasb, accf);

    stats_f32_relu_kernel<<<gstat, 256, 0, stream>>>(accf, S3);
    finalize_kernel<<<1, 256, 0, stream>>>(S3);

    final_kernel<<<g64, 256, 0, stream>>>(accf, S3, norm_g, norm_b, (float*)d_out);
}

// Round 7
// 548.850 us; speedup vs baseline: 1.5696x; 1.1970x over previous
//
#include <hip/hip_runtime.h>
#include <math.h>

typedef __bf16 bf16;
typedef __bf16 bf16x8 __attribute__((ext_vector_type(8)));
typedef float  f32x4  __attribute__((ext_vector_type(4)));

// Problem constants
constexpr int B_   = 32;
constexpr int T_   = 256;
constexpr int V_   = 25;
constexpr int NTV  = T_ * V_;                 // 6400
constexpr long long TENSOR = (long long)B_ * 128 * NTV; // 26,214,400 elems

// ws layout (float slots).
// Aliased region [0, TENSOR): xgt (bf16) + conv weights + wgb during phase 1;
// fuse_mfma overwrites it with fp32 acc (all prior tenants dead by then).
constexpr long long ACC_OFF  = 0;                        // fp32 [32][6400][128]
constexpr long long XGT_OFF  = 0;                        // bf16 [32][6400][128]
constexpr long long WRB3_OFF = XGT_OFF + TENSOR / 2;     // bf16 conv weights
constexpr long long WRB5_OFF = WRB3_OFF + 128 * 128 * 3 / 2;
constexpr long long WRB7_OFF = WRB5_OFF + 128 * 128 * 5 / 2;
constexpr long long WGB_OFF  = WRB7_OFF + 128 * 128 * 7 / 2;  // bf16 [128co][64ci]
// Non-aliased tail:
constexpr long long Y0_OFF   = ACC_OFF + TENSOR;         // bf16 x3 [32][6400][128]
constexpr long long Y1_OFF   = Y0_OFF + TENSOR / 2;
constexpr long long Y2_OFF   = Y1_OFF + TENSOR / 2;
constexpr long long XT_OFF   = Y2_OFF + TENSOR / 2;      // bf16 [32][6400][64]
constexpr long long ABIG_OFF = XT_OFF + TENSOR / 4;      // bf16 [32][128][448]
constexpr long long BIAS_OFF = ABIG_OFF + (32LL * 128 * 448) / 2; // f32 [32][128]
constexpr long long STATS_OFF = BIAS_OFF + 4096;         // 5 x 512 floats
// whbuf fp32 [204800][128] = TENSOR floats, aliases Y0+Y1 (dead before conv3 writes Y0)
constexpr long long WH_OFF   = Y0_OFF;

__device__ __forceinline__ float bflo(unsigned u) { return __builtin_bit_cast(float, u << 16); }
__device__ __forceinline__ float bfhi(unsigned u) { return __builtin_bit_cast(float, u & 0xffff0000u); }
__device__ __forceinline__ unsigned packbf2(float a, float b) {
    unsigned short ua = __builtin_bit_cast(unsigned short, (bf16)a);
    unsigned short ub = __builtin_bit_cast(unsigned short, (bf16)b);
    return (unsigned)ua | ((unsigned)ub << 16);
}

// ---------------- small prep kernels ----------------
__global__ void zero_stats_kernel(float* __restrict__ st) {
    int t = threadIdx.x;
    for (int o = t; o < 2560; o += 256) st[o] = 0.f;
}

// conv weight (co, ci, k) fp32 -> wr[co][dt][ci] bf16
__global__ void repack_wbf16_kernel(const float* __restrict__ w, bf16* __restrict__ wr, int K) {
    int idx = blockIdx.x * 256 + threadIdx.x;
    int tot = 128 * 128 * K;
    if (idx >= tot) return;
    int co  = idx / (128 * K);
    int rem = idx - co * 128 * K;
    int ci  = rem / K;
    int dt  = rem - ci * K;
    wr[(co * K + dt) * 128 + ci] = (bf16)w[idx];
}

// wg [h][c][d] fp32 -> wgb[(h*32+d)][c] bf16  (A-operand of Wh GEMM)
__global__ void repack_wgb_kernel(const float* __restrict__ wg, bf16* __restrict__ wgb) {
    int o = blockIdx.x * 256 + threadIdx.x;
    if (o >= 8192) return;
    int h = o >> 11, ci = (o >> 5) & 63, d = o & 31;
    wgb[(h * 32 + d) * 64 + ci] = (bf16)wg[o];
}

// x fp32 [b][64][n] -> xt bf16 [b][n][64]
__global__ __launch_bounds__(256) void xt_kernel(const float* __restrict__ x, bf16* __restrict__ xt) {
    __shared__ bf16 s_t[64 * 72];
    int tile = blockIdx.x, b = blockIdx.y, tid = threadIdx.x;
    int n0 = tile * 64;
#pragma unroll
    for (int it = 0; it < 4; ++it) {
        int flat = it * 256 + tid;
        int c = flat >> 4, q = flat & 15;
        float4 v = *reinterpret_cast<const float4*>(x + ((b * 64 + c) * NTV) + n0 + q * 4);
        s_t[(q * 4 + 0) * 72 + c] = (bf16)v.x;
        s_t[(q * 4 + 1) * 72 + c] = (bf16)v.y;
        s_t[(q * 4 + 2) * 72 + c] = (bf16)v.z;
        s_t[(q * 4 + 3) * 72 + c] = (bf16)v.w;
    }
    __syncthreads();
#pragma unroll
    for (int it = 0; it < 2; ++it) {
        int flat = it * 256 + tid;
        int nl = flat >> 3, c8 = flat & 7;
        uint4 v = *reinterpret_cast<const uint4*>(s_t + nl * 72 + c8 * 8);
        *reinterpret_cast<uint4*>(xt + ((long long)(b * NTV + n0 + nl)) * 64 + c8 * 8) = v;
    }
}

// ---------------- Wh GEMM: whbuf[n][128] fp32 = xt[n][64] @ wgb^T ----------------
__global__ __launch_bounds__(256) void wh_gemm_kernel(const bf16* __restrict__ xt,
                                                      const bf16* __restrict__ wgb,
                                                      float* __restrict__ whbuf) {
    __shared__ __align__(16) char s_raw[64 * 136 * 4];   // union: s_xt (8KB) then s_yf (34.8KB)
    bf16*  s_xt = reinterpret_cast<bf16*>(s_raw);
    float* s_yf = reinterpret_cast<float*>(s_raw);

    int tile = blockIdx.x, b = blockIdx.y, tid = threadIdx.x;
    long long nb0 = (long long)b * NTV + tile * 64;

    // stage 64 rows x 64 ci bf16, 16B-chunk XOR swizzle
#pragma unroll
    for (int it = 0; it < 2; ++it) {
        int flat = it * 256 + tid;
        int r = flat >> 3, ch = flat & 7;
        uint4 v = *reinterpret_cast<const uint4*>(xt + (nb0 + r) * 64 + ch * 8);
        *reinterpret_cast<uint4*>(s_xt + r * 64 + (ch ^ (r & 7)) * 8) = v;
    }
    __syncthreads();

    int wid = tid >> 6, lane = tid & 63, l15 = lane & 15, l4 = lane >> 4;
    int co0 = wid * 32;
    f32x4 acc[2][4];
#pragma unroll
    for (int m = 0; m < 2; ++m)
#pragma unroll
        for (int ns = 0; ns < 4; ++ns) acc[m][ns] = f32x4{0.f, 0.f, 0.f, 0.f};

#pragma unroll
    for (int cb = 0; cb < 2; ++cb) {
        const bf16* ap = wgb + (co0 + l15) * 64 + cb * 32 + l4 * 8;
        bf16x8 a0 = *(const bf16x8*)ap;
        bf16x8 a1 = *(const bf16x8*)(ap + 16 * 64);
#pragma unroll
        for (int ns = 0; ns < 4; ++ns) {
            int r = ns * 16 + l15;
            int chunk = (cb * 4 + l4) ^ (r & 7);
            bf16x8 bv = *(const bf16x8*)(s_xt + r * 64 + chunk * 8);
            acc[0][ns] = __builtin_amdgcn_mfma_f32_16x16x32_bf16(a0, bv, acc[0][ns], 0, 0, 0);
            acc[1][ns] = __builtin_amdgcn_mfma_f32_16x16x32_bf16(a1, bv, acc[1][ns], 0, 0, 0);
        }
    }
    __syncthreads();   // s_xt -> s_yf reuse

#pragma unroll
    for (int m = 0; m < 2; ++m)
#pragma unroll
        for (int ns = 0; ns < 4; ++ns) {
            int nl = ns * 16 + l15;
            float4 val;
            val.x = acc[m][ns][0]; val.y = acc[m][ns][1];
            val.z = acc[m][ns][2]; val.w = acc[m][ns][3];
            *reinterpret_cast<float4*>(s_yf + nl * 136 + co0 + m * 16 + l4 * 4) = val;
        }
    __syncthreads();
#pragma unroll
    for (int it = 0; it < 8; ++it) {
        int flat = it * 256 + tid;
        int nl = flat >> 5, cq = flat & 31;
        float4 v = *reinterpret_cast<const float4*>(s_yf + nl * 136 + cq * 4);
        *reinterpret_cast<float4*>(whbuf + (nb0 + nl) * 128 + cq * 4) = v;
    }
}

// ---------------- GAT attention: per (b,t), Wh precomputed -> xgt [b][n][128] ----------------
__global__ __launch_bounds__(256) void gat_att_kernel(const float* __restrict__ whbuf,
                                                      const float* __restrict__ adj,
                                                      const float* __restrict__ ag,
                                                      bf16* __restrict__ xgt) {
    __shared__ float s_wh[25 * 132];    // [v][hd], stride 132 (16B-aligned, bank-spread)
    __shared__ float s_att[101 * 28];   // [h*25+i][j], stride 28, cols 25..27 zero
    __shared__ float s_e1[100], s_e2[100];
    __shared__ float s_adj[625];

    int n = blockIdx.x;
    int b = n >> 8, t = n & 255;
    int tid = threadIdx.x;

    const float* src = whbuf + ((long long)(b * NTV + t * 25)) * 128;
    for (int o = tid; o < 800; o += 256) {
        int v = o >> 5, q = o & 31;
        float4 w = *reinterpret_cast<const float4*>(src + v * 128 + q * 4);
        *reinterpret_cast<float4*>(&s_wh[v * 132 + q * 4]) = w;
    }
    for (int o = tid; o < 625; o += 256) s_adj[o] = adj[o];
    __syncthreads();

    // e1/e2
    if (tid < 200) {
        int which = tid / 100;
        int r = tid - which * 100;
        int h = r / 25, i = r - h * 25;
        const float* a = ag + h * 64 + which * 32;
        float s = 0.f;
#pragma unroll
        for (int d = 0; d < 32; d++) s += s_wh[i * 132 + h * 32 + d] * a[d];
        if (which) s_e2[r] = s; else s_e1[r] = s;
    }
    __syncthreads();

    // masked softmax rows -> s_att (stride 28, zero-padded)
    if (tid < 100) {
        int h = tid / 25, i = tid - h * 25;
        float ei = s_e1[h * 25 + i];
        float ev[25];
        float mx = -3.4e38f;
#pragma unroll
        for (int j = 0; j < 25; j++) {
            float e = ei + s_e2[h * 25 + j];
            e = e > 0.f ? e : 0.2f * e;
            e = (s_adj[i * 25 + j] > 0.f) ? e : -9.0e15f;
            ev[j] = e;
            mx = fmaxf(mx, e);
        }
        float sum = 0.f;
#pragma unroll
        for (int j = 0; j < 25; j++) { float p = __expf(ev[j] - mx); ev[j] = p; sum += p; }
        float inv = 1.f / sum;
        int row = (h * 25 + i) * 28;
#pragma unroll
        for (int j = 0; j < 25; j++) s_att[row + j] = ev[j] * inv;
        s_att[row + 25] = 0.f; s_att[row + 26] = 0.f; s_att[row + 27] = 0.f;
    }
    __syncthreads();

    // PV: hp[v][hd] = sum_j att[h][v][j] * Wh[j][hd]
    int hd = tid & 127, vh = tid >> 7;
    int v0 = vh * 13, nv = vh ? 12 : 13;
    int h = hd >> 5;
    float whr[28];
#pragma unroll
    for (int j = 0; j < 25; ++j) whr[j] = s_wh[j * 132 + hd];
    whr[25] = 0.f; whr[26] = 0.f; whr[27] = 0.f;
    float acc[13];
#pragma unroll
    for (int i = 0; i < 13; i++) acc[i] = 0.f;
#pragma unroll
    for (int i = 0; i < 13; i++) {
        int row = (h * 25 + v0 + i) * 28;
#pragma unroll
        for (int j4 = 0; j4 < 7; ++j4) {
            float4 a4 = *reinterpret_cast<const float4*>(&s_att[row + j4 * 4]);
            acc[i] += a4.x * whr[j4 * 4] + a4.y * whr[j4 * 4 + 1]
                    + a4.z * whr[j4 * 4 + 2] + a4.w * whr[j4 * 4 + 3];
        }
    }

    // epilogue: elu -> bf16 -> xgt
    for (int i = 0; i < nv; i++) {
        float val = acc[i];
        val = val > 0.f ? val : expm1f(val);
        xgt[((long long)(b * NTV + t * 25 + v0 + i)) * 128 + hd] = (bf16)val;
    }
}

// ---------------- group stats on [b][n][128] bf16 ----------------
template <bool RELU>
__global__ __launch_bounds__(256) void stats_c128_kernel(const bf16* __restrict__ src, float* __restrict__ raw) {
    __shared__ float s_s[256], s_q[256];
    int b = blockIdx.x, sl = blockIdx.y, tid = threadIdx.x;
    int ch = tid & 15;
    const bf16* base = src + ((long long)(b * NTV + sl * 400 + (tid >> 4))) * 128 + ch * 8;
    float s = 0.f, q = 0.f;
    for (int it = 0; it < 25; ++it) {
        uint4 v = *reinterpret_cast<const uint4*>(base + (long long)it * 16 * 128);
        unsigned w[4] = {v.x, v.y, v.z, v.w};
#pragma unroll
        for (int p = 0; p < 4; ++p) {
            float f0 = bflo(w[p]), f1 = bfhi(w[p]);
            if (RELU) { f0 = fmaxf(f0, 0.f); f1 = fmaxf(f1, 0.f); }
            s += f0 + f1;
            q += f0 * f0 + f1 * f1;
        }
    }
    s_s[tid] = s; s_q[tid] = q;
    __syncthreads();
    if (tid < 8) {
        float ss = 0.f, qq = 0.f;
        for (int i = 0; i < 16; ++i) {
            int j = i * 16 + tid * 2;
            ss += s_s[j] + s_s[j + 1];
            qq += s_q[j] + s_q[j + 1];
        }
        atomicAdd(&raw[b * 8 + tid], ss);
        atomicAdd(&raw[256 + b * 8 + tid], qq);
    }
}

// group stats on [b][n][128] fp32 (with relu) — for the fused accumulator
__global__ __launch_bounds__(256) void stats_f32_relu_kernel(const float* __restrict__ src, float* __restrict__ raw) {
    __shared__ float s_s[256], s_q[256];
    int b = blockIdx.x, sl = blockIdx.y, tid = threadIdx.x;
    int cq = tid & 31;
    int r0 = sl * 400 + (tid >> 5);
    const float* base = src + ((long long)(b * NTV + r0)) * 128 + cq * 4;
    float s = 0.f, q = 0.f;
    for (int it = 0; it < 50; ++it) {
        float4 v = *reinterpret_cast<const float4*>(base + (long long)it * 8 * 128);
        float f0 = fmaxf(v.x, 0.f), f1 = fmaxf(v.y, 0.f);
        float f2 = fmaxf(v.z, 0.f), f3 = fmaxf(v.w, 0.f);
        s += f0 + f1 + f2 + f3;
        q += f0 * f0 + f1 * f1 + f2 * f2 + f3 * f3;
    }
    s_s[tid] = s; s_q[tid] = q;
    __syncthreads();
    if (tid < 8) {
        float ss = 0.f, qq = 0.f;
        for (int k = 0; k < 8; ++k)
            for (int j = 0; j < 4; ++j) {
                int t = k * 32 + tid * 4 + j;
                ss += s_s[t]; qq += s_q[t];
            }
        atomicAdd(&raw[b * 8 + tid], ss);
        atomicAdd(&raw[256 + b * 8 + tid], qq);
    }
}

__global__ void finalize_kernel(float* __restrict__ raw) {
    float* p = raw + blockIdx.x * 512;
    int t = threadIdx.x;
    float s = p[t], q = p[256 + t];
    float mu = s * (1.f / 102400.f);
    float var = q * (1.f / 102400.f) - mu * mu;
    p[t] = mu;
    p[256 + t] = rsqrtf(var + 1e-5f);
}

// ---------------- conv as MFMA GEMM (gn1+relu fused at staging) ----------------
template <int K>
__global__ __launch_bounds__(256) void conv_mfma_kernel(const bf16* __restrict__ xgt,
                                                        const bf16* __restrict__ wr,
                                                        const float* __restrict__ bb,
                                                        const float* __restrict__ g1,
                                                        const float* __restrict__ b1,
                                                        const float* __restrict__ stats1,
                                                        bf16* __restrict__ y) {
    constexpr int P = (K - 1) / 2;
    constexpr int ROWS = 128 + (K - 1) * 25;
    constexpr int NCH = ROWS * 16;
    constexpr int ITERS = (NCH + 255) / 256;
    __shared__ bf16 s_h[ROWS * 128];   // reused as s_y (128*136 <= ROWS*128 for K>=3)
    __shared__ float s_sc[128], s_bc[128];

    int tile = blockIdx.x, b = blockIdx.y, tid = threadIdx.x;
    int n0 = tile * 128;
    if (tid < 128) {
        int g = tid >> 4;
        float mu = stats1[b * 8 + g], rs = stats1[256 + b * 8 + g];
        float sc = rs * g1[tid];
        s_sc[tid] = sc;
        s_bc[tid] = b1[tid] - mu * sc;
    }
    __syncthreads();

    int ch = tid & 15;
    float sc8[8], bc8[8];
#pragma unroll
    for (int j = 0; j < 8; ++j) { sc8[j] = s_sc[ch * 8 + j]; bc8[j] = s_bc[ch * 8 + j]; }

    int nb = b * NTV;
    for (int it = 0; it < ITERS; ++it) {
        int flat = it * 256 + tid;
        if (flat < NCH) {
            int r = flat >> 4;
            int n = n0 - P * 25 + r;
            uint4 v = {0u, 0u, 0u, 0u};
            if ((unsigned)n < (unsigned)NTV)
                v = *reinterpret_cast<const uint4*>(xgt + ((long long)(nb + n)) * 128 + ch * 8);
            unsigned w[4] = {v.x, v.y, v.z, v.w};
            uint4 o;
            unsigned* op = &o.x;
#pragma unroll
            for (int p = 0; p < 4; ++p) {
                float f0 = fmaxf(bflo(w[p]) * sc8[2 * p] + bc8[2 * p], 0.f);
                float f1 = fmaxf(bfhi(w[p]) * sc8[2 * p + 1] + bc8[2 * p + 1], 0.f);
                op[p] = packbf2(f0, f1);
            }
            *reinterpret_cast<uint4*>(s_h + r * 128 + (ch ^ (r & 15)) * 8) = o;
        }
    }
    __syncthreads();

    int wid = tid >> 6, lane = tid & 63, l15 = lane & 15, l4 = lane >> 4;
    int co0 = wid * 32;
    f32x4 acc[2][8];
#pragma unroll
    for (int m = 0; m < 2; ++m)
#pragma unroll
        for (int ns = 0; ns < 8; ++ns) acc[m][ns] = f32x4{0.f, 0.f, 0.f, 0.f};

    for (int dt = 0; dt < K; ++dt) {
#pragma unroll
        for (int cb = 0; cb < 4; ++cb) {
            const bf16* ap = wr + ((co0 + l15) * K + dt) * 128 + cb * 32 + l4 * 8;
            bf16x8 a0 = *(const bf16x8*)ap;
            bf16x8 a1 = *(const bf16x8*)(ap + 16 * K * 128);
#pragma unroll
            for (int ns = 0; ns < 8; ++ns) {
                int r = ns * 16 + l15 + dt * 25;
                int chunk = (cb * 4 + l4) ^ (r & 15);
                bf16x8 bv = *(const bf16x8*)(s_h + r * 128 + chunk * 8);
                acc[0][ns] = __builtin_amdgcn_mfma_f32_16x16x32_bf16(a0, bv, acc[0][ns], 0, 0, 0);
                acc[1][ns] = __builtin_amdgcn_mfma_f32_16x16x32_bf16(a1, bv, acc[1][ns], 0, 0, 0);
            }
        }
    }
    __syncthreads();   // s_h -> s_y reuse

    bf16* sy = s_h;
    float bias[2][4];
#pragma unroll
    for (int m = 0; m < 2; ++m)
#pragma unroll
        for (int rr = 0; rr < 4; ++rr) bias[m][rr] = bb[co0 + m * 16 + l4 * 4 + rr];
#pragma unroll
    for (int m = 0; m < 2; ++m)
#pragma unroll
        for (int ns = 0; ns < 8; ++ns) {
            int nl = ns * 16 + l15;
            uint2 pk;
            pk.x = packbf2(acc[m][ns][0] + bias[m][0], acc[m][ns][1] + bias[m][1]);
            pk.y = packbf2(acc[m][ns][2] + bias[m][2], acc[m][ns][3] + bias[m][3]);
            *reinterpret_cast<uint2*>(sy + nl * 136 + co0 + m * 16 + l4 * 4) = pk;
        }
    __syncthreads();
#pragma unroll
    for (int it = 0; it < 8; ++it) {
        int flat = it * 256 + tid;
        int nl = flat >> 4, c2 = flat & 15;
        uint4 v = *reinterpret_cast<const uint4*>(sy + nl * 136 + c2 * 8);
        *reinterpret_cast<uint4*>(y + ((long long)(nb + n0 + nl)) * 128 + c2 * 8) = v;
    }
}

// ---------------- fold gn2 into fusion weights: grid (32 b, 8 co-tiles) ----------------
__global__ __launch_bounds__(256) void fold_kernel(const float* __restrict__ fus_w, const float* __restrict__ fus_b,
                                                   const float* __restrict__ res_w, const float* __restrict__ res_b,
                                                   const float* __restrict__ g20, const float* __restrict__ b20,
                                                   const float* __restrict__ g21, const float* __restrict__ b21,
                                                   const float* __restrict__ g22, const float* __restrict__ b22,
                                                   const float* __restrict__ st0, const float* __restrict__ st1,
                                                   const float* __restrict__ st2,
                                                   bf16* __restrict__ Abig, float* __restrict__ biasb) {
    __shared__ float s_sc[384], s_bc[384];
    int b = blockIdx.x, co0 = blockIdx.y * 16, tid = threadIdx.x;
    for (int o = tid; o < 384; o += 256) {
        int k = o >> 7, cc = o & 127, g = cc >> 4;
        const float* st = (k == 0) ? st0 : (k == 1) ? st1 : st2;
        const float* gg = (k == 0) ? g20 : (k == 1) ? g21 : g22;
        const float* b2 = (k == 0) ? b20 : (k == 1) ? b21 : b22;
        float mu = st[b * 8 + g], rs = st[256 + b * 8 + g];
        float sc = rs * gg[cc];
        s_sc[o] = sc;
        s_bc[o] = b2[cc] - mu * sc;
    }
    __syncthreads();

    // Abig rows co0..co0+15: coalesced sweeps, no division
#pragma unroll 1
    for (int co_l = 0; co_l < 16; ++co_l) {
        int co = co0 + co_l;
#pragma unroll
        for (int it = 0; it < 2; ++it) {
            int j = it * 256 + tid;
            if (j < 448) {
                float val = (j < 384) ? fus_w[co * 384 + j] * s_sc[j] : res_w[co * 64 + (j - 384)];
                Abig[((long long)(b * 128 + co)) * 448 + j] = (bf16)val;
            }
        }
    }

    // bias: 16 threads per co, stride-16 coalesced partials, shfl reduce within 16-lane group
    int co_l = tid >> 4, part = tid & 15;
    int co = co0 + co_l;
    float s = 0.f;
#pragma unroll
    for (int k = 0; k < 24; ++k) {
        int j = part + k * 16;
        s += fus_w[co * 384 + j] * s_bc[j];
    }
#pragma unroll
    for (int off = 1; off < 16; off <<= 1) s += __shfl_xor(s, off);
    if (part == 0)
        biasb[b * 128 + co] = fus_b[co] + res_b[co] + s;
}

// ---------------- fused output GEMM: acc(fp32) = Abig @ [y3|y5|y7|xt] + bias ----------------
__global__ __launch_bounds__(256) void fuse_mfma_kernel(const bf16* __restrict__ y0, const bf16* __restrict__ y1,
                                                        const bf16* __restrict__ y2, const bf16* __restrict__ xt,
                                                        const bf16* __restrict__ Abig, const float* __restrict__ biasb,
                                                        float* __restrict__ accf) {
    __shared__ __align__(16) bf16 s_b[64 * 448];   // B operand; reused as fp32 out-stage after MFMA
    int tile = blockIdx.x, b = blockIdx.y, tid = threadIdx.x;
    int n0 = tile * 64;

    int c = tid % 56;
    int roff = tid / 56;
    bool act = tid < 224;
    const bf16* src;
    int stride;
    if (c < 48) {
        src = (c < 16 ? y0 : (c < 32 ? y1 : y2)) + (c & 15) * 8;
        stride = 128;
    } else {
        src = xt + (c - 48) * 8;
        stride = 64;
    }
    src += (long long)(b * NTV + n0) * stride;
    if (act) {
#pragma unroll
        for (int it = 0; it < 16; ++it) {
            int r = it * 4 + roff;
            uint4 v = *reinterpret_cast<const uint4*>(src + (long long)r * stride);
            *reinterpret_cast<uint4*>(s_b + r * 448 + (c ^ (r & 7)) * 8) = v;
        }
    }
    __syncthreads();

    int wid = tid >> 6, lane = tid & 63, l15 = lane & 15, l4 = lane >> 4;
    int co0 = wid * 32;
    f32x4 acc[2][4];
#pragma unroll
    for (int m = 0; m < 2; ++m)
#pragma unroll
        for (int ns = 0; ns < 4; ++ns) acc[m][ns] = f32x4{0.f, 0.f, 0.f, 0.f};

    const bf16* abase = Abig + ((long long)(b * 128 + co0 + l15)) * 448 + l4 * 8;
#pragma unroll
    for (int ks = 0; ks < 14; ++ks) {
        bf16x8 a0 = *(const bf16x8*)(abase + ks * 32);
        bf16x8 a1 = *(const bf16x8*)(abase + 16 * 448 + ks * 32);
        int ci = ks * 4 + l4;
#pragma unroll
        for (int ns = 0; ns < 4; ++ns) {
            int r = ns * 16 + l15;
            bf16x8 bv = *(const bf16x8*)(s_b + r * 448 + (ci ^ (r & 7)) * 8);
            acc[0][ns] = __builtin_amdgcn_mfma_f32_16x16x32_bf16(a0, bv, acc[0][ns], 0, 0, 0);
            acc[1][ns] = __builtin_amdgcn_mfma_f32_16x16x32_bf16(a1, bv, acc[1][ns], 0, 0, 0);
        }
    }

    float bias[2][4];
#pragma unroll
    for (int m = 0; m < 2; ++m)
#pragma unroll
        for (int rr = 0; rr < 4; ++rr) bias[m][rr] = biasb[b * 128 + co0 + m * 16 + l4 * 4 + rr];

    __syncthreads();   // all B reads complete; reuse s_b as fp32 staging
    float* s_yf = reinterpret_cast<float*>(s_b);   // [64][136] floats = 34.8 KB
#pragma unroll
    for (int m = 0; m < 2; ++m)
#pragma unroll
        for (int ns = 0; ns < 4; ++ns) {
            int nl = ns * 16 + l15;
            float4 val;
            val.x = acc[m][ns][0] + bias[m][0];
            val.y = acc[m][ns][1] + bias[m][1];
            val.z = acc[m][ns][2] + bias[m][2];
            val.w = acc[m][ns][3] + bias[m][3];
            *reinterpret_cast<float4*>(s_yf + nl * 136 + co0 + m * 16 + l4 * 4) = val;
        }
    __syncthreads();
#pragma unroll
    for (int it = 0; it < 8; ++it) {
        int flat = it * 256 + tid;
        int nl = flat >> 5, cq = flat & 31;
        float4 v = *reinterpret_cast<const float4*>(s_yf + nl * 136 + cq * 4);
        *reinterpret_cast<float4*>(accf + ((long long)(b * NTV + n0 + nl)) * 128 + cq * 4) = v;
    }
}

// ---------------- final: out = gn3(relu(acc fp32)), transpose to [b][c][n] fp32 ----------------
__global__ __launch_bounds__(256) void final_kernel(const float* __restrict__ accf,
                                                    const float* __restrict__ stats3,
                                                    const float* __restrict__ ng,
                                                    const float* __restrict__ nb,
                                                    float* __restrict__ out) {
    __shared__ float s_o[128 * 72];
    __shared__ float s_sc[128], s_bc[128];
    int tile = blockIdx.x, b = blockIdx.y, tid = threadIdx.x;
    int n0 = tile * 64;
    if (tid < 128) {
        int g = tid >> 4;
        float mu = stats3[b * 8 + g], rs = stats3[256 + b * 8 + g];
        float sv = rs * ng[tid];
        s_sc[tid] = sv;
        s_bc[tid] = nb[tid] - mu * sv;
    }
    __syncthreads();
#pragma unroll
    for (int it = 0; it < 8; ++it) {
        int flat = it * 256 + tid;
        int r = flat >> 5, cq = flat & 31;
        float4 v = *reinterpret_cast<const float4*>(accf + ((long long)(b * NTV + n0 + r)) * 128 + cq * 4);
        float f[4] = {v.x, v.y, v.z, v.w};
#pragma unroll
        for (int p = 0; p < 4; ++p) {
            int ci = cq * 4 + p;
            s_o[ci * 72 + r] = fmaxf(f[p], 0.f) * s_sc[ci] + s_bc[ci];
        }
    }
    __syncthreads();
#pragma unroll
    for (int it = 0; it < 8; ++it) {
        int flat = it * 256 + tid;
        int ci = flat >> 4, q = flat & 15;
        float4 v = *reinterpret_cast<const float4*>(s_o + ci * 72 + q * 4);
        *reinterpret_cast<float4*>(out + ((long long)(b * 128 + ci)) * NTV + n0 + q * 4) = v;
    }
}

extern "C" void kernel_launch(void* const* d_in, const int* in_sizes, int n_in,
                              void* d_out, int out_size, void* d_ws, size_t ws_size,
                              hipStream_t stream) {
    const float* x      = (const float*)d_in[0];
    const float* adj    = (const float*)d_in[1];
    const float* w_gat  = (const float*)d_in[2];
    const float* a_gat  = (const float*)d_in[3];
    const float* fus_w  = (const float*)d_in[4];
    const float* fus_b  = (const float*)d_in[5];
    const float* res_w  = (const float*)d_in[6];
    const float* res_b  = (const float*)d_in[7];
    const float* norm_g = (const float*)d_in[8];
    const float* norm_b = (const float*)d_in[9];
    const float* tg1[3], *tb1[3], *tw[3], *tbb[3], *tg2[3], *tb2[3];
    for (int i = 0; i < 3; i++) {
        tg1[i] = (const float*)d_in[10 + 6 * i + 0];
        tb1[i] = (const float*)d_in[10 + 6 * i + 1];
        tw[i]  = (const float*)d_in[10 + 6 * i + 2];
        tbb[i] = (const float*)d_in[10 + 6 * i + 3];
        tg2[i] = (const float*)d_in[10 + 6 * i + 4];
        tb2[i] = (const float*)d_in[10 + 6 * i + 5];
    }

    float* ws = (float*)d_ws;
    float* accf  = ws + ACC_OFF;                    // fp32, aliases xgt/wrb/wgb (dead by fuse)
    bf16* xgt    = (bf16*)(ws + XGT_OFF);
    bf16* wrb[3] = { (bf16*)(ws + WRB3_OFF), (bf16*)(ws + WRB5_OFF), (bf16*)(ws + WRB7_OFF) };
    bf16* wgb    = (bf16*)(ws + WGB_OFF);
    float* whbuf = ws + WH_OFF;                     // fp32, aliases Y0+Y1 (dead before conv3)
    bf16* yb[3]  = { (bf16*)(ws + Y0_OFF), (bf16*)(ws + Y1_OFF), (bf16*)(ws + Y2_OFF) };
    bf16* xt     = (bf16*)(ws + XT_OFF);
    bf16* Abig   = (bf16*)(ws + ABIG_OFF);
    float* biasb = ws + BIAS_OFF;
    float* S1    = ws + STATS_OFF;
    float* S2    = S1 + 512;      // 3 consecutive buffers
    float* S3    = S1 + 2048;

    const int Ks[3] = { 3, 5, 7 };

    zero_stats_kernel<<<1, 256, 0, stream>>>(S1);
    for (int i = 0; i < 3; i++) {
        int tot = 128 * 128 * Ks[i];
        repack_wbf16_kernel<<<(tot + 255) / 256, 256, 0, stream>>>(tw[i], wrb[i], Ks[i]);
    }
    repack_wgb_kernel<<<32, 256, 0, stream>>>(w_gat, wgb);

    dim3 g64(100, 32), g128(50, 32), gstat(32, 16);

    xt_kernel<<<g64, 256, 0, stream>>>(x, xt);

    // GAT = Wh GEMM (MFMA) + attention kernel
    wh_gemm_kernel<<<g64, 256, 0, stream>>>(xt, wgb, whbuf);
    gat_att_kernel<<<B_ * T_, 256, 0, stream>>>(whbuf, adj, a_gat, xgt);

    stats_c128_kernel<false><<<gstat, 256, 0, stream>>>(xgt, S1);
    finalize_kernel<<<1, 256, 0, stream>>>(S1);

    conv_mfma_kernel<3><<<g128, 256, 0, stream>>>(xgt, wrb[0], tbb[0], tg1[0], tb1[0], S1, yb[0]);
    conv_mfma_kernel<5><<<g128, 256, 0, stream>>>(xgt, wrb[1], tbb[1], tg1[1], tb1[1], S1, yb[1]);
    conv_mfma_kernel<7><<<g128, 256, 0, stream>>>(xgt, wrb[2], tbb[2], tg1[2], tb1[2], S1, yb[2]);

    stats_c128_kernel<false><<<gstat, 256, 0, stream>>>(yb[0], S2);
    stats_c128_kernel<false><<<gstat, 256, 0, stream>>>(yb[1], S2 + 512);
    stats_c128_kernel<false><<<gstat, 256, 0, stream>>>(yb[2], S2 + 1024);
    finalize_kernel<<<3, 256, 0, stream>>>(S2);

    fold_kernel<<<dim3(32, 8), 256, 0, stream>>>(fus_w, fus_b, res_w, res_b,
                                                 tg2[0], tb2[0], tg2[1], tb2[1], tg2[2], tb2[2],
                                                 S2, S2 + 512, S2 + 1024, Abig, biasb);

    // fuse overwrites the xgt/wrb/wgb region with fp32 acc (those are dead now)
    fuse_mfma_kernel<<<g64, 256, 0, stream>>>(yb[0], yb[1], yb[2], xt, Abig, biasb, accf);

    stats_f32_relu_kernel<<<gstat, 256, 0, stream>>>(accf, S3);
    finalize_kernel<<<1, 256, 0, stream>>>(S3);

    final_kernel<<<g64, 256, 0, stream>>>(accf, S3, norm_g, norm_b, (float*)d_out);
}

// Round 8
// 516.647 us; speedup vs baseline: 1.6674x; 1.0623x over previous
//
#include <hip/hip_runtime.h>
#include <math.h>

typedef __bf16 bf16;
typedef __bf16 bf16x8 __attribute__((ext_vector_type(8)));
typedef float  f32x4  __attribute__((ext_vector_type(4)));

// Problem constants
constexpr int B_   = 32;
constexpr int T_   = 256;
constexpr int V_   = 25;
constexpr int NTV  = T_ * V_;                 // 6400
constexpr long long TENSOR = (long long)B_ * 128 * NTV; // 26,214,400 elems

// ws layout (float slots).
// Aliased region [0, TENSOR): xgt (bf16) + conv weights + wgb during phase 1;
// fuse_mfma overwrites it with fp32 acc (all prior tenants dead by then).
constexpr long long ACC_OFF  = 0;                        // fp32 [32][6400][128]
constexpr long long XGT_OFF  = 0;                        // bf16 [32][6400][128]
constexpr long long WRB3_OFF = XGT_OFF + TENSOR / 2;     // bf16 conv weights (lane-major)
constexpr long long WRB5_OFF = WRB3_OFF + 128 * 128 * 3 / 2;
constexpr long long WRB7_OFF = WRB5_OFF + 128 * 128 * 5 / 2;
constexpr long long WGB_OFF  = WRB7_OFF + 128 * 128 * 7 / 2;  // bf16 [128co][64ci]
// Non-aliased tail:
constexpr long long Y0_OFF   = ACC_OFF + TENSOR;         // bf16 x3 [32][6400][128]
constexpr long long Y1_OFF   = Y0_OFF + TENSOR / 2;
constexpr long long Y2_OFF   = Y1_OFF + TENSOR / 2;
constexpr long long XT_OFF   = Y2_OFF + TENSOR / 2;      // bf16 [32][6400][64]
constexpr long long ABIG_OFF = XT_OFF + TENSOR / 4;      // bf16 [32][8][14][64][8] lane-major
constexpr long long BIAS_OFF = ABIG_OFF + (32LL * 128 * 448) / 2; // f32 [32][128]
constexpr long long STATS_OFF = BIAS_OFF + 4096;         // 5 x 512 floats
// whbuf fp32 [204800][128] = TENSOR floats, aliases Y0+Y1 (dead before conv3 writes Y0)
constexpr long long WH_OFF   = Y0_OFF;

__device__ __forceinline__ float bflo(unsigned u) { return __builtin_bit_cast(float, u << 16); }
__device__ __forceinline__ float bfhi(unsigned u) { return __builtin_bit_cast(float, u & 0xffff0000u); }
__device__ __forceinline__ unsigned packbf2(float a, float b) {
    unsigned short ua = __builtin_bit_cast(unsigned short, (bf16)a);
    unsigned short ub = __builtin_bit_cast(unsigned short, (bf16)b);
    return (unsigned)ua | ((unsigned)ub << 16);
}

// ---------------- small prep kernels ----------------
__global__ void zero_stats_kernel(float* __restrict__ st) {
    int t = threadIdx.x;
    for (int o = t; o < 2560; o += 256) st[o] = 0.f;
}

// conv weight (co, ci, k) fp32 -> lane-major bf16:
// wr[(((cb_co*K + dt)*4 + cb)*64 + lane)*8 + e], co = cb_co*16 + (lane&15),
// ci = cb*32 + (lane>>4)*8 + e.  Per-fragment loads are then 64-lane contiguous.
__global__ void repack_wbf16_kernel(const float* __restrict__ w, bf16* __restrict__ wr, int K) {
    int idx = blockIdx.x * 256 + threadIdx.x;
    int tot = 128 * 128 * K;
    if (idx >= tot) return;
    int e    = idx & 7;
    int lane = (idx >> 3) & 63;
    int rem  = idx >> 9;          // (cb_co*K + dt)*4 + cb
    int cb   = rem & 3;
    int rem2 = rem >> 2;          // cb_co*K + dt
    int dt   = rem2 % K;
    int cb_co = rem2 / K;
    int l15 = lane & 15, l4 = lane >> 4;
    int co = cb_co * 16 + l15;
    int ci = cb * 32 + l4 * 8 + e;
    wr[idx] = (bf16)w[(co * 128 + ci) * K + dt];
}

// wg [h][c][d] fp32 -> wgb[(h*32+d)][c] bf16  (A-operand of Wh GEMM)
__global__ void repack_wgb_kernel(const float* __restrict__ wg, bf16* __restrict__ wgb) {
    int o = blockIdx.x * 256 + threadIdx.x;
    if (o >= 8192) return;
    int h = o >> 11, ci = (o >> 5) & 63, d = o & 31;
    wgb[(h * 32 + d) * 64 + ci] = (bf16)wg[o];
}

// x fp32 [b][64][n] -> xt bf16 [b][n][64]
__global__ __launch_bounds__(256) void xt_kernel(const float* __restrict__ x, bf16* __restrict__ xt) {
    __shared__ bf16 s_t[64 * 72];
    int tile = blockIdx.x, b = blockIdx.y, tid = threadIdx.x;
    int n0 = tile * 64;
#pragma unroll
    for (int it = 0; it < 4; ++it) {
        int flat = it * 256 + tid;
        int c = flat >> 4, q = flat & 15;
        float4 v = *reinterpret_cast<const float4*>(x + ((b * 64 + c) * NTV) + n0 + q * 4);
        s_t[(q * 4 + 0) * 72 + c] = (bf16)v.x;
        s_t[(q * 4 + 1) * 72 + c] = (bf16)v.y;
        s_t[(q * 4 + 2) * 72 + c] = (bf16)v.z;
        s_t[(q * 4 + 3) * 72 + c] = (bf16)v.w;
    }
    __syncthreads();
#pragma unroll
    for (int it = 0; it < 2; ++it) {
        int flat = it * 256 + tid;
        int nl = flat >> 3, c8 = flat & 7;
        uint4 v = *reinterpret_cast<const uint4*>(s_t + nl * 72 + c8 * 8);
        *reinterpret_cast<uint4*>(xt + ((long long)(b * NTV + n0 + nl)) * 64 + c8 * 8) = v;
    }
}

// ---------------- Wh GEMM: whbuf[n][128] fp32 = xt[n][64] @ wgb^T ----------------
__global__ __launch_bounds__(256) void wh_gemm_kernel(const bf16* __restrict__ xt,
                                                      const bf16* __restrict__ wgb,
                                                      float* __restrict__ whbuf) {
    __shared__ __align__(16) char s_raw[64 * 136 * 4];   // union: s_xt (8KB) then s_yf (34.8KB)
    bf16*  s_xt = reinterpret_cast<bf16*>(s_raw);
    float* s_yf = reinterpret_cast<float*>(s_raw);

    int tile = blockIdx.x, b = blockIdx.y, tid = threadIdx.x;
    long long nb0 = (long long)b * NTV + tile * 64;

    // stage 64 rows x 64 ci bf16, 16B-chunk XOR swizzle
#pragma unroll
    for (int it = 0; it < 2; ++it) {
        int flat = it * 256 + tid;
        int r = flat >> 3, ch = flat & 7;
        uint4 v = *reinterpret_cast<const uint4*>(xt + (nb0 + r) * 64 + ch * 8);
        *reinterpret_cast<uint4*>(s_xt + r * 64 + (ch ^ (r & 7)) * 8) = v;
    }
    __syncthreads();

    int wid = tid >> 6, lane = tid & 63, l15 = lane & 15, l4 = lane >> 4;
    int co0 = wid * 32;
    f32x4 acc[2][4];
#pragma unroll
    for (int m = 0; m < 2; ++m)
#pragma unroll
        for (int ns = 0; ns < 4; ++ns) acc[m][ns] = f32x4{0.f, 0.f, 0.f, 0.f};

#pragma unroll
    for (int cb = 0; cb < 2; ++cb) {
        const bf16* ap = wgb + (co0 + l15) * 64 + cb * 32 + l4 * 8;
        bf16x8 a0 = *(const bf16x8*)ap;
        bf16x8 a1 = *(const bf16x8*)(ap + 16 * 64);
#pragma unroll
        for (int ns = 0; ns < 4; ++ns) {
            int r = ns * 16 + l15;
            int chunk = (cb * 4 + l4) ^ (r & 7);
            bf16x8 bv = *(const bf16x8*)(s_xt + r * 64 + chunk * 8);
            acc[0][ns] = __builtin_amdgcn_mfma_f32_16x16x32_bf16(a0, bv, acc[0][ns], 0, 0, 0);
            acc[1][ns] = __builtin_amdgcn_mfma_f32_16x16x32_bf16(a1, bv, acc[1][ns], 0, 0, 0);
        }
    }
    __syncthreads();   // s_xt -> s_yf reuse

#pragma unroll
    for (int m = 0; m < 2; ++m)
#pragma unroll
        for (int ns = 0; ns < 4; ++ns) {
            int nl = ns * 16 + l15;
            float4 val;
            val.x = acc[m][ns][0]; val.y = acc[m][ns][1];
            val.z = acc[m][ns][2]; val.w = acc[m][ns][3];
            *reinterpret_cast<float4*>(s_yf + nl * 136 + co0 + m * 16 + l4 * 4) = val;
        }
    __syncthreads();
#pragma unroll
    for (int it = 0; it < 8; ++it) {
        int flat = it * 256 + tid;
        int nl = flat >> 5, cq = flat & 31;
        float4 v = *reinterpret_cast<const float4*>(s_yf + nl * 136 + cq * 4);
        *reinterpret_cast<float4*>(whbuf + (nb0 + nl) * 128 + cq * 4) = v;
    }
}

// ---------------- GAT attention: per (b,t), Wh precomputed -> xgt [b][n][128] ----------------
__global__ __launch_bounds__(256) void gat_att_kernel(const float* __restrict__ whbuf,
                                                      const float* __restrict__ adj,
                                                      const float* __restrict__ ag,
                                                      bf16* __restrict__ xgt) {
    __shared__ float s_wh[25 * 132];    // [v][hd], stride 132 (16B-aligned, bank-spread)
    __shared__ float s_att[101 * 28];   // [h*25+i][j], stride 28, cols 25..27 zero
    __shared__ float s_e1[100], s_e2[100];
    __shared__ float s_adj[625];

    int n = blockIdx.x;
    int b = n >> 8, t = n & 255;
    int tid = threadIdx.x;

    const float* src = whbuf + ((long long)(b * NTV + t * 25)) * 128;
    for (int o = tid; o < 800; o += 256) {
        int v = o >> 5, q = o & 31;
        float4 w = *reinterpret_cast<const float4*>(src + v * 128 + q * 4);
        *reinterpret_cast<float4*>(&s_wh[v * 132 + q * 4]) = w;
    }
    for (int o = tid; o < 625; o += 256) s_adj[o] = adj[o];
    __syncthreads();

    // e1/e2
    if (tid < 200) {
        int which = tid / 100;
        int r = tid - which * 100;
        int h = r / 25, i = r - h * 25;
        const float* a = ag + h * 64 + which * 32;
        float s = 0.f;
#pragma unroll
        for (int d = 0; d < 32; d++) s += s_wh[i * 132 + h * 32 + d] * a[d];
        if (which) s_e2[r] = s; else s_e1[r] = s;
    }
    __syncthreads();

    // masked softmax rows -> s_att (stride 28, zero-padded)
    if (tid < 100) {
        int h = tid / 25, i = tid - h * 25;
        float ei = s_e1[h * 25 + i];
        float ev[25];
        float mx = -3.4e38f;
#pragma unroll
        for (int j = 0; j < 25; j++) {
            float e = ei + s_e2[h * 25 + j];
            e = e > 0.f ? e : 0.2f * e;
            e = (s_adj[i * 25 + j] > 0.f) ? e : -9.0e15f;
            ev[j] = e;
            mx = fmaxf(mx, e);
        }
        float sum = 0.f;
#pragma unroll
        for (int j = 0; j < 25; j++) { float p = __expf(ev[j] - mx); ev[j] = p; sum += p; }
        float inv = 1.f / sum;
        int row = (h * 25 + i) * 28;
#pragma unroll
        for (int j = 0; j < 25; j++) s_att[row + j] = ev[j] * inv;
        s_att[row + 25] = 0.f; s_att[row + 26] = 0.f; s_att[row + 27] = 0.f;
    }
    __syncthreads();

    // PV: hp[v][hd] = sum_j att[h][v][j] * Wh[j][hd]
    int hd = tid & 127, vh = tid >> 7;
    int v0 = vh * 13, nv = vh ? 12 : 13;
    int h = hd >> 5;
    float whr[28];
#pragma unroll
    for (int j = 0; j < 25; ++j) whr[j] = s_wh[j * 132 + hd];
    whr[25] = 0.f; whr[26] = 0.f; whr[27] = 0.f;
    float acc[13];
#pragma unroll
    for (int i = 0; i < 13; i++) acc[i] = 0.f;
#pragma unroll
    for (int i = 0; i < 13; i++) {
        int row = (h * 25 + v0 + i) * 28;
#pragma unroll
        for (int j4 = 0; j4 < 7; ++j4) {
            float4 a4 = *reinterpret_cast<const float4*>(&s_att[row + j4 * 4]);
            acc[i] += a4.x * whr[j4 * 4] + a4.y * whr[j4 * 4 + 1]
                    + a4.z * whr[j4 * 4 + 2] + a4.w * whr[j4 * 4 + 3];
        }
    }

    // epilogue: elu -> bf16 -> xgt
    for (int i = 0; i < nv; i++) {
        float val = acc[i];
        val = val > 0.f ? val : expm1f(val);
        xgt[((long long)(b * NTV + t * 25 + v0 + i)) * 128 + hd] = (bf16)val;
    }
}

// ---------------- group stats on [b][n][128] bf16 ----------------
template <bool RELU>
__global__ __launch_bounds__(256) void stats_c128_kernel(const bf16* __restrict__ src, float* __restrict__ raw) {
    __shared__ float s_s[256], s_q[256];
    int b = blockIdx.x, sl = blockIdx.y, tid = threadIdx.x;
    int ch = tid & 15;
    const bf16* base = src + ((long long)(b * NTV + sl * 400 + (tid >> 4))) * 128 + ch * 8;
    float s = 0.f, q = 0.f;
    for (int it = 0; it < 25; ++it) {
        uint4 v = *reinterpret_cast<const uint4*>(base + (long long)it * 16 * 128);
        unsigned w[4] = {v.x, v.y, v.z, v.w};
#pragma unroll
        for (int p = 0; p < 4; ++p) {
            float f0 = bflo(w[p]), f1 = bfhi(w[p]);
            if (RELU) { f0 = fmaxf(f0, 0.f); f1 = fmaxf(f1, 0.f); }
            s += f0 + f1;
            q += f0 * f0 + f1 * f1;
        }
    }
    s_s[tid] = s; s_q[tid] = q;
    __syncthreads();
    if (tid < 8) {
        float ss = 0.f, qq = 0.f;
        for (int i = 0; i < 16; ++i) {
            int j = i * 16 + tid * 2;
            ss += s_s[j] + s_s[j + 1];
            qq += s_q[j] + s_q[j + 1];
        }
        atomicAdd(&raw[b * 8 + tid], ss);
        atomicAdd(&raw[256 + b * 8 + tid], qq);
    }
}

// group stats on [b][n][128] fp32 (with relu) — for the fused accumulator
__global__ __launch_bounds__(256) void stats_f32_relu_kernel(const float* __restrict__ src, float* __restrict__ raw) {
    __shared__ float s_s[256], s_q[256];
    int b = blockIdx.x, sl = blockIdx.y, tid = threadIdx.x;
    int cq = tid & 31;
    int r0 = sl * 400 + (tid >> 5);
    const float* base = src + ((long long)(b * NTV + r0)) * 128 + cq * 4;
    float s = 0.f, q = 0.f;
    for (int it = 0; it < 50; ++it) {
        float4 v = *reinterpret_cast<const float4*>(base + (long long)it * 8 * 128);
        float f0 = fmaxf(v.x, 0.f), f1 = fmaxf(v.y, 0.f);
        float f2 = fmaxf(v.z, 0.f), f3 = fmaxf(v.w, 0.f);
        s += f0 + f1 + f2 + f3;
        q += f0 * f0 + f1 * f1 + f2 * f2 + f3 * f3;
    }
    s_s[tid] = s; s_q[tid] = q;
    __syncthreads();
    if (tid < 8) {
        float ss = 0.f, qq = 0.f;
        for (int k = 0; k < 8; ++k)
            for (int j = 0; j < 4; ++j) {
                int t = k * 32 + tid * 4 + j;
                ss += s_s[t]; qq += s_q[t];
            }
        atomicAdd(&raw[b * 8 + tid], ss);
        atomicAdd(&raw[256 + b * 8 + tid], qq);
    }
}

__global__ void finalize_kernel(float* __restrict__ raw) {
    float* p = raw + blockIdx.x * 512;
    int t = threadIdx.x;
    float s = p[t], q = p[256 + t];
    float mu = s * (1.f / 102400.f);
    float var = q * (1.f / 102400.f) - mu * mu;
    p[t] = mu;
    p[256 + t] = rsqrtf(var + 1e-5f);
}

// ---------------- conv as MFMA GEMM (gn1+relu fused at staging; lane-major A) ----------------
template <int K>
__global__ __launch_bounds__(256) void conv_mfma_kernel(const bf16* __restrict__ xgt,
                                                        const bf16* __restrict__ wr,
                                                        const float* __restrict__ bb,
                                                        const float* __restrict__ g1,
                                                        const float* __restrict__ b1,
                                                        const float* __restrict__ stats1,
                                                        bf16* __restrict__ y) {
    constexpr int P = (K - 1) / 2;
    constexpr int ROWS = 128 + (K - 1) * 25;
    constexpr int NCH = ROWS * 16;
    constexpr int ITERS = (NCH + 255) / 256;
    __shared__ bf16 s_h[ROWS * 128];   // reused as s_y (128*136 <= ROWS*128 for K>=3)
    __shared__ float s_sc[128], s_bc[128];

    int tile = blockIdx.x, b = blockIdx.y, tid = threadIdx.x;
    int n0 = tile * 128;
    if (tid < 128) {
        int g = tid >> 4;
        float mu = stats1[b * 8 + g], rs = stats1[256 + b * 8 + g];
        float sc = rs * g1[tid];
        s_sc[tid] = sc;
        s_bc[tid] = b1[tid] - mu * sc;
    }
    __syncthreads();

    int ch = tid & 15;
    float sc8[8], bc8[8];
#pragma unroll
    for (int j = 0; j < 8; ++j) { sc8[j] = s_sc[ch * 8 + j]; bc8[j] = s_bc[ch * 8 + j]; }

    int nb = b * NTV;
    for (int it = 0; it < ITERS; ++it) {
        int flat = it * 256 + tid;
        if (flat < NCH) {
            int r = flat >> 4;
            int n = n0 - P * 25 + r;
            uint4 v = {0u, 0u, 0u, 0u};
            if ((unsigned)n < (unsigned)NTV)
                v = *reinterpret_cast<const uint4*>(xgt + ((long long)(nb + n)) * 128 + ch * 8);
            unsigned w[4] = {v.x, v.y, v.z, v.w};
            uint4 o;
            unsigned* op = &o.x;
#pragma unroll
            for (int p = 0; p < 4; ++p) {
                float f0 = fmaxf(bflo(w[p]) * sc8[2 * p] + bc8[2 * p], 0.f);
                float f1 = fmaxf(bfhi(w[p]) * sc8[2 * p + 1] + bc8[2 * p + 1], 0.f);
                op[p] = packbf2(f0, f1);
            }
            *reinterpret_cast<uint4*>(s_h + r * 128 + (ch ^ (r & 15)) * 8) = o;
        }
    }
    __syncthreads();

    int wid = tid >> 6, lane = tid & 63, l15 = lane & 15, l4 = lane >> 4;
    int co0 = wid * 32;
    f32x4 acc[2][8];
#pragma unroll
    for (int m = 0; m < 2; ++m)
#pragma unroll
        for (int ns = 0; ns < 8; ++ns) acc[m][ns] = f32x4{0.f, 0.f, 0.f, 0.f};

    // lane-major A: wr[(((cb_co*K + dt)*4 + cb)*64 + lane)*8]
    const bf16* wrA = wr + lane * 8;
    for (int dt = 0; dt < K; ++dt) {
#pragma unroll
        for (int cb = 0; cb < 4; ++cb) {
            bf16x8 a0 = *(const bf16x8*)(wrA + (((wid * 2 + 0) * K + dt) * 4 + cb) * 512);
            bf16x8 a1 = *(const bf16x8*)(wrA + (((wid * 2 + 1) * K + dt) * 4 + cb) * 512);
#pragma unroll
            for (int ns = 0; ns < 8; ++ns) {
                int r = ns * 16 + l15 + dt * 25;
                int chunk = (cb * 4 + l4) ^ (r & 15);
                bf16x8 bv = *(const bf16x8*)(s_h + r * 128 + chunk * 8);
                acc[0][ns] = __builtin_amdgcn_mfma_f32_16x16x32_bf16(a0, bv, acc[0][ns], 0, 0, 0);
                acc[1][ns] = __builtin_amdgcn_mfma_f32_16x16x32_bf16(a1, bv, acc[1][ns], 0, 0, 0);
            }
        }
    }
    __syncthreads();   // s_h -> s_y reuse

    bf16* sy = s_h;
    float bias[2][4];
#pragma unroll
    for (int m = 0; m < 2; ++m)
#pragma unroll
        for (int rr = 0; rr < 4; ++rr) bias[m][rr] = bb[co0 + m * 16 + l4 * 4 + rr];
#pragma unroll
    for (int m = 0; m < 2; ++m)
#pragma unroll
        for (int ns = 0; ns < 8; ++ns) {
            int nl = ns * 16 + l15;
            uint2 pk;
            pk.x = packbf2(acc[m][ns][0] + bias[m][0], acc[m][ns][1] + bias[m][1]);
            pk.y = packbf2(acc[m][ns][2] + bias[m][2], acc[m][ns][3] + bias[m][3]);
            *reinterpret_cast<uint2*>(sy + nl * 136 + co0 + m * 16 + l4 * 4) = pk;
        }
    __syncthreads();
#pragma unroll
    for (int it = 0; it < 8; ++it) {
        int flat = it * 256 + tid;
        int nl = flat >> 4, c2 = flat & 15;
        uint4 v = *reinterpret_cast<const uint4*>(sy + nl * 136 + c2 * 8);
        *reinterpret_cast<uint4*>(y + ((long long)(nb + n0 + nl)) * 128 + c2 * 8) = v;
    }
}

// ---------------- fold gn2 into fusion weights: grid (32 b, 8 cb_co) ----------------
// Abig lane-major: Abig[(((b*8 + cb_co)*14 + ks)*64 + lane)*8 + e],
// co = cb_co*16 + (lane&15), j = ks*32 + (lane>>4)*8 + e.
__global__ __launch_bounds__(256) void fold_kernel(const float* __restrict__ fus_w, const float* __restrict__ fus_b,
                                                   const float* __restrict__ res_w, const float* __restrict__ res_b,
                                                   const float* __restrict__ g20, const float* __restrict__ b20,
                                                   const float* __restrict__ g21, const float* __restrict__ b21,
                                                   const float* __restrict__ g22, const float* __restrict__ b22,
                                                   const float* __restrict__ st0, const float* __restrict__ st1,
                                                   const float* __restrict__ st2,
                                                   bf16* __restrict__ Abig, float* __restrict__ biasb) {
    __shared__ float s_sc[384], s_bc[384];
    int b = blockIdx.x, cb_co = blockIdx.y, tid = threadIdx.x;
    int co0 = cb_co * 16;
    for (int o = tid; o < 384; o += 256) {
        int k = o >> 7, cc = o & 127, g = cc >> 4;
        const float* st = (k == 0) ? st0 : (k == 1) ? st1 : st2;
        const float* gg = (k == 0) ? g20 : (k == 1) ? g21 : g22;
        const float* b2 = (k == 0) ? b20 : (k == 1) ? b21 : b22;
        float mu = st[b * 8 + g], rs = st[256 + b * 8 + g];
        float sc = rs * gg[cc];
        s_sc[o] = sc;
        s_bc[o] = b2[cc] - mu * sc;
    }
    __syncthreads();

    // fill this (b, cb_co) block of Abig: 7168 elems, output-linear (coalesced writes)
    bf16* abase = Abig + ((long long)(b * 8 + cb_co)) * 14 * 512;
#pragma unroll 1
    for (int it = 0; it < 28; ++it) {
        int o = it * 256 + tid;           // o = (ks*64 + lane)*8 + e
        int e = o & 7;
        int lane = (o >> 3) & 63;
        int ks = o >> 9;
        int l15 = lane & 15, l4 = lane >> 4;
        int co = co0 + l15;
        int j = ks * 32 + l4 * 8 + e;
        float val = (j < 384) ? fus_w[co * 384 + j] * s_sc[j] : res_w[co * 64 + (j - 384)];
        abase[o] = (bf16)val;
    }

    // bias: 16 threads per co, stride-16 coalesced partials, shfl reduce within 16-lane group
    int co_l = tid >> 4, part = tid & 15;
    int co = co0 + co_l;
    float s = 0.f;
#pragma unroll
    for (int k = 0; k < 24; ++k) {
        int j = part + k * 16;
        s += fus_w[co * 384 + j] * s_bc[j];
    }
#pragma unroll
    for (int off = 1; off < 16; off <<= 1) s += __shfl_xor(s, off);
    if (part == 0)
        biasb[b * 128 + co] = fus_b[co] + res_b[co] + s;
}

// ---------------- fused output GEMM: acc(fp32) = Abig @ [y3|y5|y7|xt] + bias ----------------
__global__ __launch_bounds__(256) void fuse_mfma_kernel(const bf16* __restrict__ y0, const bf16* __restrict__ y1,
                                                        const bf16* __restrict__ y2, const bf16* __restrict__ xt,
                                                        const bf16* __restrict__ Abig, const float* __restrict__ biasb,
                                                        float* __restrict__ accf) {
    __shared__ __align__(16) bf16 s_b[64 * 448];   // B operand; reused as fp32 out-stage after MFMA
    int tile = blockIdx.x, b = blockIdx.y, tid = threadIdx.x;
    int n0 = tile * 64;

    int c = tid % 56;
    int roff = tid / 56;
    bool act = tid < 224;
    const bf16* src;
    int stride;
    if (c < 48) {
        src = (c < 16 ? y0 : (c < 32 ? y1 : y2)) + (c & 15) * 8;
        stride = 128;
    } else {
        src = xt + (c - 48) * 8;
        stride = 64;
    }
    src += (long long)(b * NTV + n0) * stride;
    if (act) {
#pragma unroll
        for (int it = 0; it < 16; ++it) {
            int r = it * 4 + roff;
            uint4 v = *reinterpret_cast<const uint4*>(src + (long long)r * stride);
            *reinterpret_cast<uint4*>(s_b + r * 448 + (c ^ (r & 7)) * 8) = v;
        }
    }
    __syncthreads();

    int wid = tid >> 6, lane = tid & 63, l15 = lane & 15, l4 = lane >> 4;
    int co0 = wid * 32;
    f32x4 acc[2][4];
#pragma unroll
    for (int m = 0; m < 2; ++m)
#pragma unroll
        for (int ns = 0; ns < 4; ++ns) acc[m][ns] = f32x4{0.f, 0.f, 0.f, 0.f};

    // lane-major A: Abig[(((b*8 + cb_co)*14 + ks)*64 + lane)*8]
    const bf16* abase = Abig + (((long long)(b * 8 + wid * 2)) * 14 * 64 + lane) * 8;
#pragma unroll
    for (int ks = 0; ks < 14; ++ks) {
        bf16x8 a0 = *(const bf16x8*)(abase + ks * 512);
        bf16x8 a1 = *(const bf16x8*)(abase + 14 * 512 + ks * 512);
        int ci = ks * 4 + l4;
#pragma unroll
        for (int ns = 0; ns < 4; ++ns) {
            int r = ns * 16 + l15;
            bf16x8 bv = *(const bf16x8*)(s_b + r * 448 + (ci ^ (r & 7)) * 8);
            acc[0][ns] = __builtin_amdgcn_mfma_f32_16x16x32_bf16(a0, bv, acc[0][ns], 0, 0, 0);
            acc[1][ns] = __builtin_amdgcn_mfma_f32_16x16x32_bf16(a1, bv, acc[1][ns], 0, 0, 0);
        }
    }

    float bias[2][4];
#pragma unroll
    for (int m = 0; m < 2; ++m)
#pragma unroll
        for (int rr = 0; rr < 4; ++rr) bias[m][rr] = biasb[b * 128 + co0 + m * 16 + l4 * 4 + rr];

    __syncthreads();   // all B reads complete; reuse s_b as fp32 staging
    float* s_yf = reinterpret_cast<float*>(s_b);   // [64][136] floats = 34.8 KB
#pragma unroll
    for (int m = 0; m < 2; ++m)
#pragma unroll
        for (int ns = 0; ns < 4; ++ns) {
            int nl = ns * 16 + l15;
            float4 val;
            val.x = acc[m][ns][0] + bias[m][0];
            val.y = acc[m][ns][1] + bias[m][1];
            val.z = acc[m][ns][2] + bias[m][2];
            val.w = acc[m][ns][3] + bias[m][3];
            *reinterpret_cast<float4*>(s_yf + nl * 136 + co0 + m * 16 + l4 * 4) = val;
        }
    __syncthreads();
#pragma unroll
    for (int it = 0; it < 8; ++it) {
        int flat = it * 256 + tid;
        int nl = flat >> 5, cq = flat & 31;
        float4 v = *reinterpret_cast<const float4*>(s_yf + nl * 136 + cq * 4);
        *reinterpret_cast<float4*>(accf + ((long long)(b * NTV + n0 + nl)) * 128 + cq * 4) = v;
    }
}

// ---------------- final: out = gn3(relu(acc fp32)), transpose to [b][c][n] fp32 ----------------
__global__ __launch_bounds__(256) void final_kernel(const float* __restrict__ accf,
                                                    const float* __restrict__ stats3,
                                                    const float* __restrict__ ng,
                                                    const float* __restrict__ nb,
                                                    float* __restrict__ out) {
    __shared__ float s_o[128 * 72];
    __shared__ float s_sc[128], s_bc[128];
    int tile = blockIdx.x, b = blockIdx.y, tid = threadIdx.x;
    int n0 = tile * 64;
    if (tid < 128) {
        int g = tid >> 4;
        float mu = stats3[b * 8 + g], rs = stats3[256 + b * 8 + g];
        float sv = rs * ng[tid];
        s_sc[tid] = sv;
        s_bc[tid] = nb[tid] - mu * sv;
    }
    __syncthreads();
#pragma unroll
    for (int it = 0; it < 8; ++it) {
        int flat = it * 256 + tid;
        int r = flat >> 5, cq = flat & 31;
        float4 v = *reinterpret_cast<const float4*>(accf + ((long long)(b * NTV + n0 + r)) * 128 + cq * 4);
        float f[4] = {v.x, v.y, v.z, v.w};
#pragma unroll
        for (int p = 0; p < 4; ++p) {
            int ci = cq * 4 + p;
            s_o[ci * 72 + r] = fmaxf(f[p], 0.f) * s_sc[ci] + s_bc[ci];
        }
    }
    __syncthreads();
#pragma unroll
    for (int it = 0; it < 8; ++it) {
        int flat = it * 256 + tid;
        int ci = flat >> 4, q = flat & 15;
        float4 v = *reinterpret_cast<const float4*>(s_o + ci * 72 + q * 4);
        *reinterpret_cast<float4*>(out + ((long long)(b * 128 + ci)) * NTV + n0 + q * 4) = v;
    }
}

extern "C" void kernel_launch(void* const* d_in, const int* in_sizes, int n_in,
                              void* d_out, int out_size, void* d_ws, size_t ws_size,
                              hipStream_t stream) {
    const float* x      = (const float*)d_in[0];
    const float* adj    = (const float*)d_in[1];
    const float* w_gat  = (const float*)d_in[2];
    const float* a_gat  = (const float*)d_in[3];
    const float* fus_w  = (const float*)d_in[4];
    const float* fus_b  = (const float*)d_in[5];
    const float* res_w  = (const float*)d_in[6];
    const float* res_b  = (const float*)d_in[7];
    const float* norm_g = (const float*)d_in[8];
    const float* norm_b = (const float*)d_in[9];
    const float* tg1[3], *tb1[3], *tw[3], *tbb[3], *tg2[3], *tb2[3];
    for (int i = 0; i < 3; i++) {
        tg1[i] = (const float*)d_in[10 + 6 * i + 0];
        tb1[i] = (const float*)d_in[10 + 6 * i + 1];
        tw[i]  = (const float*)d_in[10 + 6 * i + 2];
        tbb[i] = (const float*)d_in[10 + 6 * i + 3];
        tg2[i] = (const float*)d_in[10 + 6 * i + 4];
        tb2[i] = (const float*)d_in[10 + 6 * i + 5];
    }

    float* ws = (float*)d_ws;
    float* accf  = ws + ACC_OFF;                    // fp32, aliases xgt/wrb/wgb (dead by fuse)
    bf16* xgt    = (bf16*)(ws + XGT_OFF);
    bf16* wrb[3] = { (bf16*)(ws + WRB3_OFF), (bf16*)(ws + WRB5_OFF), (bf16*)(ws + WRB7_OFF) };
    bf16* wgb    = (bf16*)(ws + WGB_OFF);
    float* whbuf = ws + WH_OFF;                     // fp32, aliases Y0+Y1 (dead before conv3)
    bf16* yb[3]  = { (bf16*)(ws + Y0_OFF), (bf16*)(ws + Y1_OFF), (bf16*)(ws + Y2_OFF) };
    bf16* xt     = (bf16*)(ws + XT_OFF);
    bf16* Abig   = (bf16*)(ws + ABIG_OFF);
    float* biasb = ws + BIAS_OFF;
    float* S1    = ws + STATS_OFF;
    float* S2    = S1 + 512;      // 3 consecutive buffers
    float* S3    = S1 + 2048;

    const int Ks[3] = { 3, 5, 7 };

    zero_stats_kernel<<<1, 256, 0, stream>>>(S1);
    for (int i = 0; i < 3; i++) {
        int tot = 128 * 128 * Ks[i];
        repack_wbf16_kernel<<<(tot + 255) / 256, 256, 0, stream>>>(tw[i], wrb[i], Ks[i]);
    }
    repack_wgb_kernel<<<32, 256, 0, stream>>>(w_gat, wgb);

    dim3 g64(100, 32), g128(50, 32), gstat(32, 16);

    xt_kernel<<<g64, 256, 0, stream>>>(x, xt);

    // GAT = Wh GEMM (MFMA) + attention kernel
    wh_gemm_kernel<<<g64, 256, 0, stream>>>(xt, wgb, whbuf);
    gat_att_kernel<<<B_ * T_, 256, 0, stream>>>(whbuf, adj, a_gat, xgt);

    stats_c128_kernel<false><<<gstat, 256, 0, stream>>>(xgt, S1);
    finalize_kernel<<<1, 256, 0, stream>>>(S1);

    conv_mfma_kernel<3><<<g128, 256, 0, stream>>>(xgt, wrb[0], tbb[0], tg1[0], tb1[0], S1, yb[0]);
    conv_mfma_kernel<5><<<g128, 256, 0, stream>>>(xgt, wrb[1], tbb[1], tg1[1], tb1[1], S1, yb[1]);
    conv_mfma_kernel<7><<<g128, 256, 0, stream>>>(xgt, wrb[2], tbb[2], tg1[2], tb1[2], S1, yb[2]);

    stats_c128_kernel<false><<<gstat, 256, 0, stream>>>(yb[0], S2);
    stats_c128_kernel<false><<<gstat, 256, 0, stream>>>(yb[1], S2 + 512);
    stats_c128_kernel<false><<<gstat, 256, 0, stream>>>(yb[2], S2 + 1024);
    finalize_kernel<<<3, 256, 0, stream>>>(S2);

    fold_kernel<<<dim3(32, 8), 256, 0, stream>>>(fus_w, fus_b, res_w, res_b,
                                                 tg2[0], tb2[0], tg2[1], tb2[1], tg2[2], tb2[2],
                                                 S2, S2 + 512, S2 + 1024, Abig, biasb);

    // fuse overwrites the xgt/wrb/wgb region with fp32 acc (those are dead now)
    fuse_mfma_kernel<<<g64, 256, 0, stream>>>(yb[0], yb[1], yb[2], xt, Abig, biasb, accf);

    stats_f32_relu_kernel<<<gstat, 256, 0, stream>>>(accf, S3);
    finalize_kernel<<<1, 256, 0, stream>>>(S3);

    final_kernel<<<g64, 256, 0, stream>>>(accf, S3, norm_g, norm_b, (float*)d_out);
}

// Round 9
// 491.500 us; speedup vs baseline: 1.7528x; 1.0512x over previous
//
#include <hip/hip_runtime.h>
#include <math.h>

typedef __bf16 bf16;
typedef __bf16 bf16x8 __attribute__((ext_vector_type(8)));
typedef float  f32x4  __attribute__((ext_vector_type(4)));

// Problem constants
constexpr int B_   = 32;
constexpr int T_   = 256;
constexpr int V_   = 25;
constexpr int NTV  = T_ * V_;                 // 6400
constexpr long long TENSOR = (long long)B_ * 128 * NTV; // 26,214,400 elems

// ws layout (float slots).
// Aliased region [0, TENSOR): xgt (bf16) + conv weights + wgbl during phase 1;
// fuse_mfma overwrites it with fp32 acc (all prior tenants dead by then).
constexpr long long ACC_OFF  = 0;                        // fp32 [32][6400][128]
constexpr long long XGT_OFF  = 0;                        // bf16 [32][6400][128]
constexpr long long WRB3_OFF = XGT_OFF + TENSOR / 2;     // bf16 conv weights (lane-major)
constexpr long long WRB5_OFF = WRB3_OFF + 128 * 128 * 3 / 2;
constexpr long long WRB7_OFF = WRB5_OFF + 128 * 128 * 5 / 2;
constexpr long long WGB_OFF  = WRB7_OFF + 128 * 128 * 7 / 2;  // bf16 wgbl lane-major (16 KB)
// Non-aliased tail:
constexpr long long Y0_OFF   = ACC_OFF + TENSOR;         // bf16 x3 [32][6400][128]
constexpr long long Y1_OFF   = Y0_OFF + TENSOR / 2;
constexpr long long Y2_OFF   = Y1_OFF + TENSOR / 2;
constexpr long long XT_OFF   = Y2_OFF + TENSOR / 2;      // bf16 [32][6400][64]
constexpr long long ABIG_OFF = XT_OFF + TENSOR / 4;      // bf16 [32][8][14][64][8] lane-major
constexpr long long BIAS_OFF = ABIG_OFF + (32LL * 128 * 448) / 2; // f32 [32][128]
constexpr long long STATS_OFF = BIAS_OFF + 4096;         // 5 x 512 floats

__device__ __forceinline__ float bflo(unsigned u) { return __builtin_bit_cast(float, u << 16); }
__device__ __forceinline__ float bfhi(unsigned u) { return __builtin_bit_cast(float, u & 0xffff0000u); }
__device__ __forceinline__ unsigned packbf2(float a, float b) {
    unsigned short ua = __builtin_bit_cast(unsigned short, (bf16)a);
    unsigned short ub = __builtin_bit_cast(unsigned short, (bf16)b);
    return (unsigned)ua | ((unsigned)ub << 16);
}

// ---------------- small prep kernels ----------------
__global__ void zero_stats_kernel(float* __restrict__ st) {
    int t = threadIdx.x;
    for (int o = t; o < 2560; o += 256) st[o] = 0.f;
}

// conv weight (co, ci, k) fp32 -> lane-major bf16:
// wr[(((cb_co*K + dt)*4 + cb)*64 + lane)*8 + e], co = cb_co*16 + (lane&15),
// ci = cb*32 + (lane>>4)*8 + e.  Per-fragment loads are then 64-lane contiguous.
__global__ void repack_wbf16_kernel(const float* __restrict__ w, bf16* __restrict__ wr, int K) {
    int idx = blockIdx.x * 256 + threadIdx.x;
    int tot = 128 * 128 * K;
    if (idx >= tot) return;
    int e    = idx & 7;
    int lane = (idx >> 3) & 63;
    int rem  = idx >> 9;          // (cb_co*K + dt)*4 + cb
    int cb   = rem & 3;
    int rem2 = rem >> 2;          // cb_co*K + dt
    int dt   = rem2 % K;
    int cb_co = rem2 / K;
    int l15 = lane & 15, l4 = lane >> 4;
    int co = cb_co * 16 + l15;
    int ci = cb * 32 + l4 * 8 + e;
    wr[idx] = (bf16)w[(co * 128 + ci) * K + dt];
}

// wg [h][c][d] fp32 -> lane-major bf16 wgbl[((cb_co*2+cb)*64+lane)*8+e],
// co = cb_co*16 + (lane&15) (co = h*32+d), ci = cb*32 + (lane>>4)*8 + e.
__global__ void repack_wgbl_kernel(const float* __restrict__ wg, bf16* __restrict__ wgbl) {
    int idx = blockIdx.x * 256 + threadIdx.x;
    if (idx >= 8192) return;
    int e = idx & 7;
    int lane = (idx >> 3) & 63;
    int q = idx >> 9;             // cb_co*2 + cb
    int cb_co = q >> 1, cb = q & 1;
    int co = cb_co * 16 + (lane & 15);
    int ci = cb * 32 + (lane >> 4) * 8 + e;
    int h = co >> 5, d = co & 31;
    wgbl[idx] = (bf16)wg[h * 2048 + ci * 32 + d];
}

// x fp32 [b][64][n] -> xt bf16 [b][n][64]
__global__ __launch_bounds__(256) void xt_kernel(const float* __restrict__ x, bf16* __restrict__ xt) {
    __shared__ bf16 s_t[64 * 72];
    int tile = blockIdx.x, b = blockIdx.y, tid = threadIdx.x;
    int n0 = tile * 64;
#pragma unroll
    for (int it = 0; it < 4; ++it) {
        int flat = it * 256 + tid;
        int c = flat >> 4, q = flat & 15;
        float4 v = *reinterpret_cast<const float4*>(x + ((b * 64 + c) * NTV) + n0 + q * 4);
        s_t[(q * 4 + 0) * 72 + c] = (bf16)v.x;
        s_t[(q * 4 + 1) * 72 + c] = (bf16)v.y;
        s_t[(q * 4 + 2) * 72 + c] = (bf16)v.z;
        s_t[(q * 4 + 3) * 72 + c] = (bf16)v.w;
    }
    __syncthreads();
#pragma unroll
    for (int it = 0; it < 2; ++it) {
        int flat = it * 256 + tid;
        int nl = flat >> 3, c8 = flat & 7;
        uint4 v = *reinterpret_cast<const uint4*>(s_t + nl * 72 + c8 * 8);
        *reinterpret_cast<uint4*>(xt + ((long long)(b * NTV + n0 + nl)) * 64 + c8 * 8) = v;
    }
}

// ---------------- fused GAT: per (b,t) — Wh via MFMA, e via shfl, softmax, PV ----------------
__global__ __launch_bounds__(256) void gat_fused_kernel(const bf16* __restrict__ xt,
                                                        const bf16* __restrict__ wgbl,
                                                        const float* __restrict__ adj,
                                                        const float* __restrict__ ag,
                                                        bf16* __restrict__ xgt) {
    __shared__ __align__(16) bf16 s_xt[32 * 64];   // 25 rows + 7 zero-pad, swizzled
    __shared__ float s_wh[25 * 132];               // [v][hd] fp32
    __shared__ float s_att[100 * 28];              // [h*25+i][j], cols 25..27 zero
    __shared__ float s_e1[100], s_e2[100];         // [i*4 + h]
    __shared__ float s_adj[625];

    int tile = blockIdx.x, b = blockIdx.y, tid = threadIdx.x;
    long long nb0 = (long long)b * NTV + tile * 25;

    // stage xt rows 0..24 (zero 25..31), 16B-chunk XOR swizzle
    {
        int r = tid >> 3, ch = tid & 7;
        uint4 v = {0u, 0u, 0u, 0u};
        if (r < 25) v = *reinterpret_cast<const uint4*>(xt + (nb0 + r) * 64 + ch * 8);
        *reinterpret_cast<uint4*>(s_xt + r * 64 + (ch ^ (r & 7)) * 8) = v;
    }
    for (int o = tid; o < 625; o += 256) s_adj[o] = adj[o];
    __syncthreads();

    int wid = tid >> 6, lane = tid & 63, l15 = lane & 15, l4 = lane >> 4;
    int co0 = wid * 32;

    // Wh MFMA: rows 0..31 (25 real), cols co0..co0+31
    f32x4 acc[2][2];
#pragma unroll
    for (int m = 0; m < 2; ++m)
#pragma unroll
        for (int ns = 0; ns < 2; ++ns) acc[m][ns] = f32x4{0.f, 0.f, 0.f, 0.f};
#pragma unroll
    for (int cb = 0; cb < 2; ++cb) {
        bf16x8 a0 = *(const bf16x8*)(wgbl + (((wid * 2 + 0) * 2 + cb) * 64 + lane) * 8);
        bf16x8 a1 = *(const bf16x8*)(wgbl + (((wid * 2 + 1) * 2 + cb) * 64 + lane) * 8);
#pragma unroll
        for (int ns = 0; ns < 2; ++ns) {
            int r = ns * 16 + l15;
            int chunk = (cb * 4 + l4) ^ (r & 7);
            bf16x8 bv = *(const bf16x8*)(s_xt + r * 64 + chunk * 8);
            acc[0][ns] = __builtin_amdgcn_mfma_f32_16x16x32_bf16(a0, bv, acc[0][ns], 0, 0, 0);
            acc[1][ns] = __builtin_amdgcn_mfma_f32_16x16x32_bf16(a1, bv, acc[1][ns], 0, 0, 0);
        }
    }

    // e1/e2 from registers (head = wid): lane covers d = m*16 + l4*4 + r4; reduce over l4
    float4 a1v[2], a2v[2];
#pragma unroll
    for (int m = 0; m < 2; ++m) {
        a1v[m] = *reinterpret_cast<const float4*>(ag + wid * 64 + m * 16 + l4 * 4);
        a2v[m] = *reinterpret_cast<const float4*>(ag + wid * 64 + 32 + m * 16 + l4 * 4);
    }
#pragma unroll
    for (int ns = 0; ns < 2; ++ns) {
        int r = ns * 16 + l15;
        if (r < 25) {
            *reinterpret_cast<float4*>(&s_wh[r * 132 + co0 + l4 * 4]) =
                float4{acc[0][ns][0], acc[0][ns][1], acc[0][ns][2], acc[0][ns][3]};
            *reinterpret_cast<float4*>(&s_wh[r * 132 + co0 + 16 + l4 * 4]) =
                float4{acc[1][ns][0], acc[1][ns][1], acc[1][ns][2], acc[1][ns][3]};
        }
        float pe1 = acc[0][ns][0] * a1v[0].x + acc[0][ns][1] * a1v[0].y
                  + acc[0][ns][2] * a1v[0].z + acc[0][ns][3] * a1v[0].w
                  + acc[1][ns][0] * a1v[1].x + acc[1][ns][1] * a1v[1].y
                  + acc[1][ns][2] * a1v[1].z + acc[1][ns][3] * a1v[1].w;
        float pe2 = acc[0][ns][0] * a2v[0].x + acc[0][ns][1] * a2v[0].y
                  + acc[0][ns][2] * a2v[0].z + acc[0][ns][3] * a2v[0].w
                  + acc[1][ns][0] * a2v[1].x + acc[1][ns][1] * a2v[1].y
                  + acc[1][ns][2] * a2v[1].z + acc[1][ns][3] * a2v[1].w;
        pe1 += __shfl_xor(pe1, 16); pe1 += __shfl_xor(pe1, 32);
        pe2 += __shfl_xor(pe2, 16); pe2 += __shfl_xor(pe2, 32);
        if (l4 == 0 && r < 25) { s_e1[r * 4 + wid] = pe1; s_e2[r * 4 + wid] = pe2; }
    }
    __syncthreads();

    // masked softmax rows -> s_att (stride 28, zero-padded)
    if (tid < 100) {
        int h = tid / 25, i = tid - h * 25;
        float ei = s_e1[i * 4 + h];
        float ev[25];
        float mx = -3.4e38f;
#pragma unroll
        for (int j = 0; j < 25; j++) {
            float e = ei + s_e2[j * 4 + h];
            e = e > 0.f ? e : 0.2f * e;
            e = (s_adj[i * 25 + j] > 0.f) ? e : -9.0e15f;
            ev[j] = e;
            mx = fmaxf(mx, e);
        }
        float sum = 0.f;
#pragma unroll
        for (int j = 0; j < 25; j++) { float p = __expf(ev[j] - mx); ev[j] = p; sum += p; }
        float inv = 1.f / sum;
        int row = (h * 25 + i) * 28;
#pragma unroll
        for (int j = 0; j < 25; j++) s_att[row + j] = ev[j] * inv;
        s_att[row + 25] = 0.f; s_att[row + 26] = 0.f; s_att[row + 27] = 0.f;
    }
    __syncthreads();

    // PV: hp[v][hd] = sum_j att[h][v][j] * Wh[j][hd]   (fp32)
    int hd = tid & 127, vh = tid >> 7;
    int v0 = vh * 13, nv = vh ? 12 : 13;
    int h = hd >> 5;
    float whr[28];
#pragma unroll
    for (int j = 0; j < 25; ++j) whr[j] = s_wh[j * 132 + hd];
    whr[25] = 0.f; whr[26] = 0.f; whr[27] = 0.f;
    float accp[13];
#pragma unroll
    for (int i = 0; i < 13; i++) accp[i] = 0.f;
#pragma unroll
    for (int i = 0; i < 13; i++) {
        int row = (h * 25 + v0 + i) * 28;
#pragma unroll
        for (int j4 = 0; j4 < 7; ++j4) {
            float4 a4 = *reinterpret_cast<const float4*>(&s_att[row + j4 * 4]);
            accp[i] += a4.x * whr[j4 * 4] + a4.y * whr[j4 * 4 + 1]
                     + a4.z * whr[j4 * 4 + 2] + a4.w * whr[j4 * 4 + 3];
        }
    }

    // epilogue: elu -> bf16 -> xgt
    for (int i = 0; i < nv; i++) {
        float val = accp[i];
        val = val > 0.f ? val : expm1f(val);
        xgt[(nb0 + v0 + i) * 128 + hd] = (bf16)val;
    }
}

// ---------------- group stats on [b][n][128] bf16 ----------------
template <bool RELU>
__global__ __launch_bounds__(256) void stats_c128_kernel(const bf16* __restrict__ src, float* __restrict__ raw) {
    __shared__ float s_s[256], s_q[256];
    int b = blockIdx.x, sl = blockIdx.y, tid = threadIdx.x;
    int ch = tid & 15;
    const bf16* base = src + ((long long)(b * NTV + sl * 400 + (tid >> 4))) * 128 + ch * 8;
    float s = 0.f, q = 0.f;
    for (int it = 0; it < 25; ++it) {
        uint4 v = *reinterpret_cast<const uint4*>(base + (long long)it * 16 * 128);
        unsigned w[4] = {v.x, v.y, v.z, v.w};
#pragma unroll
        for (int p = 0; p < 4; ++p) {
            float f0 = bflo(w[p]), f1 = bfhi(w[p]);
            if (RELU) { f0 = fmaxf(f0, 0.f); f1 = fmaxf(f1, 0.f); }
            s += f0 + f1;
            q += f0 * f0 + f1 * f1;
        }
    }
    s_s[tid] = s; s_q[tid] = q;
    __syncthreads();
    if (tid < 8) {
        float ss = 0.f, qq = 0.f;
        for (int i = 0; i < 16; ++i) {
            int j = i * 16 + tid * 2;
            ss += s_s[j] + s_s[j + 1];
            qq += s_q[j] + s_q[j + 1];
        }
        atomicAdd(&raw[b * 8 + tid], ss);
        atomicAdd(&raw[256 + b * 8 + tid], qq);
    }
}

// group stats on [b][n][128] fp32 (with relu) — for the fused accumulator
__global__ __launch_bounds__(256) void stats_f32_relu_kernel(const float* __restrict__ src, float* __restrict__ raw) {
    __shared__ float s_s[256], s_q[256];
    int b = blockIdx.x, sl = blockIdx.y, tid = threadIdx.x;
    int cq = tid & 31;
    int r0 = sl * 400 + (tid >> 5);
    const float* base = src + ((long long)(b * NTV + r0)) * 128 + cq * 4;
    float s = 0.f, q = 0.f;
    for (int it = 0; it < 50; ++it) {
        float4 v = *reinterpret_cast<const float4*>(base + (long long)it * 8 * 128);
        float f0 = fmaxf(v.x, 0.f), f1 = fmaxf(v.y, 0.f);
        float f2 = fmaxf(v.z, 0.f), f3 = fmaxf(v.w, 0.f);
        s += f0 + f1 + f2 + f3;
        q += f0 * f0 + f1 * f1 + f2 * f2 + f3 * f3;
    }
    s_s[tid] = s; s_q[tid] = q;
    __syncthreads();
    if (tid < 8) {
        float ss = 0.f, qq = 0.f;
        for (int k = 0; k < 8; ++k)
            for (int j = 0; j < 4; ++j) {
                int t = k * 32 + tid * 4 + j;
                ss += s_s[t]; qq += s_q[t];
            }
        atomicAdd(&raw[b * 8 + tid], ss);
        atomicAdd(&raw[256 + b * 8 + tid], qq);
    }
}

__global__ void finalize_kernel(float* __restrict__ raw) {
    float* p = raw + blockIdx.x * 512;
    int t = threadIdx.x;
    float s = p[t], q = p[256 + t];
    float mu = s * (1.f / 102400.f);
    float var = q * (1.f / 102400.f) - mu * mu;
    p[t] = mu;
    p[256 + t] = rsqrtf(var + 1e-5f);
}

// ---------------- conv as MFMA GEMM (gn1+relu fused at staging; lane-major A) ----------------
template <int K>
__global__ __launch_bounds__(256) void conv_mfma_kernel(const bf16* __restrict__ xgt,
                                                        const bf16* __restrict__ wr,
                                                        const float* __restrict__ bb,
                                                        const float* __restrict__ g1,
                                                        const float* __restrict__ b1,
                                                        const float* __restrict__ stats1,
                                                        bf16* __restrict__ y) {
    constexpr int P = (K - 1) / 2;
    constexpr int ROWS = 128 + (K - 1) * 25;
    constexpr int NCH = ROWS * 16;
    constexpr int ITERS = (NCH + 255) / 256;
    __shared__ bf16 s_h[ROWS * 128];   // reused as s_y (128*136 <= ROWS*128 for K>=3)
    __shared__ float s_sc[128], s_bc[128];

    int tile = blockIdx.x, b = blockIdx.y, tid = threadIdx.x;
    int n0 = tile * 128;
    if (tid < 128) {
        int g = tid >> 4;
        float mu = stats1[b * 8 + g], rs = stats1[256 + b * 8 + g];
        float sc = rs * g1[tid];
        s_sc[tid] = sc;
        s_bc[tid] = b1[tid] - mu * sc;
    }
    __syncthreads();

    int ch = tid & 15;
    float sc8[8], bc8[8];
#pragma unroll
    for (int j = 0; j < 8; ++j) { sc8[j] = s_sc[ch * 8 + j]; bc8[j] = s_bc[ch * 8 + j]; }

    int nb = b * NTV;
    for (int it = 0; it < ITERS; ++it) {
        int flat = it * 256 + tid;
        if (flat < NCH) {
            int r = flat >> 4;
            int n = n0 - P * 25 + r;
            uint4 v = {0u, 0u, 0u, 0u};
            if ((unsigned)n < (unsigned)NTV)
                v = *reinterpret_cast<const uint4*>(xgt + ((long long)(nb + n)) * 128 + ch * 8);
            unsigned w[4] = {v.x, v.y, v.z, v.w};
            uint4 o;
            unsigned* op = &o.x;
#pragma unroll
            for (int p = 0; p < 4; ++p) {
                float f0 = fmaxf(bflo(w[p]) * sc8[2 * p] + bc8[2 * p], 0.f);
                float f1 = fmaxf(bfhi(w[p]) * sc8[2 * p + 1] + bc8[2 * p + 1], 0.f);
                op[p] = packbf2(f0, f1);
            }
            *reinterpret_cast<uint4*>(s_h + r * 128 + (ch ^ (r & 15)) * 8) = o;
        }
    }
    __syncthreads();

    int wid = tid >> 6, lane = tid & 63, l15 = lane & 15, l4 = lane >> 4;
    int co0 = wid * 32;
    f32x4 acc[2][8];
#pragma unroll
    for (int m = 0; m < 2; ++m)
#pragma unroll
        for (int ns = 0; ns < 8; ++ns) acc[m][ns] = f32x4{0.f, 0.f, 0.f, 0.f};

    // lane-major A: wr[(((cb_co*K + dt)*4 + cb)*64 + lane)*8]
    const bf16* wrA = wr + lane * 8;
    for (int dt = 0; dt < K; ++dt) {
#pragma unroll
        for (int cb = 0; cb < 4; ++cb) {
            bf16x8 a0 = *(const bf16x8*)(wrA + (((wid * 2 + 0) * K + dt) * 4 + cb) * 512);
            bf16x8 a1 = *(const bf16x8*)(wrA + (((wid * 2 + 1) * K + dt) * 4 + cb) * 512);
#pragma unroll
            for (int ns = 0; ns < 8; ++ns) {
                int r = ns * 16 + l15 + dt * 25;
                int chunk = (cb * 4 + l4) ^ (r & 15);
                bf16x8 bv = *(const bf16x8*)(s_h + r * 128 + chunk * 8);
                acc[0][ns] = __builtin_amdgcn_mfma_f32_16x16x32_bf16(a0, bv, acc[0][ns], 0, 0, 0);
                acc[1][ns] = __builtin_amdgcn_mfma_f32_16x16x32_bf16(a1, bv, acc[1][ns], 0, 0, 0);
            }
        }
    }
    __syncthreads();   // s_h -> s_y reuse

    bf16* sy = s_h;
    float bias[2][4];
#pragma unroll
    for (int m = 0; m < 2; ++m)
#pragma unroll
        for (int rr = 0; rr < 4; ++rr) bias[m][rr] = bb[co0 + m * 16 + l4 * 4 + rr];
#pragma unroll
    for (int m = 0; m < 2; ++m)
#pragma unroll
        for (int ns = 0; ns < 8; ++ns) {
            int nl = ns * 16 + l15;
            uint2 pk;
            pk.x = packbf2(acc[m][ns][0] + bias[m][0], acc[m][ns][1] + bias[m][1]);
            pk.y = packbf2(acc[m][ns][2] + bias[m][2], acc[m][ns][3] + bias[m][3]);
            *reinterpret_cast<uint2*>(sy + nl * 136 + co0 + m * 16 + l4 * 4) = pk;
        }
    __syncthreads();
#pragma unroll
    for (int it = 0; it < 8; ++it) {
        int flat = it * 256 + tid;
        int nl = flat >> 4, c2 = flat & 15;
        uint4 v = *reinterpret_cast<const uint4*>(sy + nl * 136 + c2 * 8);
        *reinterpret_cast<uint4*>(y + ((long long)(nb + n0 + nl)) * 128 + c2 * 8) = v;
    }
}

// ---------------- fold gn2 into fusion weights: grid (32 b, 8 cb_co) ----------------
// Abig lane-major: Abig[(((b*8 + cb_co)*14 + ks)*64 + lane)*8 + e],
// co = cb_co*16 + (lane&15), j = ks*32 + (lane>>4)*8 + e.
__global__ __launch_bounds__(256) void fold_kernel(const float* __restrict__ fus_w, const float* __restrict__ fus_b,
                                                   const float* __restrict__ res_w, const float* __restrict__ res_b,
                                                   const float* __restrict__ g20, const float* __restrict__ b20,
                                                   const float* __restrict__ g21, const float* __restrict__ b21,
                                                   const float* __restrict__ g22, const float* __restrict__ b22,
                                                   const float* __restrict__ st0, const float* __restrict__ st1,
                                                   const float* __restrict__ st2,
                                                   bf16* __restrict__ Abig, float* __restrict__ biasb) {
    __shared__ float s_sc[384], s_bc[384];
    int b = blockIdx.x, cb_co = blockIdx.y, tid = threadIdx.x;
    int co0 = cb_co * 16;
    for (int o = tid; o < 384; o += 256) {
        int k = o >> 7, cc = o & 127, g = cc >> 4;
        const float* st = (k == 0) ? st0 : (k == 1) ? st1 : st2;
        const float* gg = (k == 0) ? g20 : (k == 1) ? g21 : g22;
        const float* b2 = (k == 0) ? b20 : (k == 1) ? b21 : b22;
        float mu = st[b * 8 + g], rs = st[256 + b * 8 + g];
        float sc = rs * gg[cc];
        s_sc[o] = sc;
        s_bc[o] = b2[cc] - mu * sc;
    }
    __syncthreads();

    // fill this (b, cb_co) block of Abig: 7168 elems, output-linear (coalesced writes)
    bf16* abase = Abig + ((long long)(b * 8 + cb_co)) * 14 * 512;
#pragma unroll 1
    for (int it = 0; it < 28; ++it) {
        int o = it * 256 + tid;           // o = (ks*64 + lane)*8 + e
        int e = o & 7;
        int lane = (o >> 3) & 63;
        int ks = o >> 9;
        int l15 = lane & 15, l4 = lane >> 4;
        int co = co0 + l15;
        int j = ks * 32 + l4 * 8 + e;
        float val = (j < 384) ? fus_w[co * 384 + j] * s_sc[j] : res_w[co * 64 + (j - 384)];
        abase[o] = (bf16)val;
    }

    // bias: 16 threads per co, stride-16 coalesced partials, shfl reduce within 16-lane group
    int co_l = tid >> 4, part = tid & 15;
    int co = co0 + co_l;
    float s = 0.f;
#pragma unroll
    for (int k = 0; k < 24; ++k) {
        int j = part + k * 16;
        s += fus_w[co * 384 + j] * s_bc[j];
    }
#pragma unroll
    for (int off = 1; off < 16; off <<= 1) s += __shfl_xor(s, off);
    if (part == 0)
        biasb[b * 128 + co] = fus_b[co] + res_b[co] + s;
}

// ---------------- fused output GEMM: acc(fp32) = Abig @ [y3|y5|y7|xt] + bias ----------------
__global__ __launch_bounds__(256) void fuse_mfma_kernel(const bf16* __restrict__ y0, const bf16* __restrict__ y1,
                                                        const bf16* __restrict__ y2, const bf16* __restrict__ xt,
                                                        const bf16* __restrict__ Abig, const float* __restrict__ biasb,
                                                        float* __restrict__ accf) {
    __shared__ __align__(16) bf16 s_b[64 * 448];   // B operand; reused as fp32 out-stage after MFMA
    int tile = blockIdx.x, b = blockIdx.y, tid = threadIdx.x;
    int n0 = tile * 64;

    int c = tid % 56;
    int roff = tid / 56;
    bool act = tid < 224;
    const bf16* src;
    int stride;
    if (c < 48) {
        src = (c < 16 ? y0 : (c < 32 ? y1 : y2)) + (c & 15) * 8;
        stride = 128;
    } else {
        src = xt + (c - 48) * 8;
        stride = 64;
    }
    src += (long long)(b * NTV + n0) * stride;
    if (act) {
#pragma unroll
        for (int it = 0; it < 16; ++it) {
            int r = it * 4 + roff;
            uint4 v = *reinterpret_cast<const uint4*>(src + (long long)r * stride);
            *reinterpret_cast<uint4*>(s_b + r * 448 + (c ^ (r & 7)) * 8) = v;
        }
    }
    __syncthreads();

    int wid = tid >> 6, lane = tid & 63, l15 = lane & 15, l4 = lane >> 4;
    int co0 = wid * 32;
    f32x4 acc[2][4];
#pragma unroll
    for (int m = 0; m < 2; ++m)
#pragma unroll
        for (int ns = 0; ns < 4; ++ns) acc[m][ns] = f32x4{0.f, 0.f, 0.f, 0.f};

    // lane-major A: Abig[(((b*8 + cb_co)*14 + ks)*64 + lane)*8]
    const bf16* abase = Abig + (((long long)(b * 8 + wid * 2)) * 14 * 64 + lane) * 8;
#pragma unroll
    for (int ks = 0; ks < 14; ++ks) {
        bf16x8 a0 = *(const bf16x8*)(abase + ks * 512);
        bf16x8 a1 = *(const bf16x8*)(abase + 14 * 512 + ks * 512);
        int ci = ks * 4 + l4;
#pragma unroll
        for (int ns = 0; ns < 4; ++ns) {
            int r = ns * 16 + l15;
            bf16x8 bv = *(const bf16x8*)(s_b + r * 448 + (ci ^ (r & 7)) * 8);
            acc[0][ns] = __builtin_amdgcn_mfma_f32_16x16x32_bf16(a0, bv, acc[0][ns], 0, 0, 0);
            acc[1][ns] = __builtin_amdgcn_mfma_f32_16x16x32_bf16(a1, bv, acc[1][ns], 0, 0, 0);
        }
    }

    float bias[2][4];
#pragma unroll
    for (int m = 0; m < 2; ++m)
#pragma unroll
        for (int rr = 0; rr < 4; ++rr) bias[m][rr] = biasb[b * 128 + co0 + m * 16 + l4 * 4 + rr];

    __syncthreads();   // all B reads complete; reuse s_b as fp32 staging
    float* s_yf = reinterpret_cast<float*>(s_b);   // [64][136] floats = 34.8 KB
#pragma unroll
    for (int m = 0; m < 2; ++m)
#pragma unroll
        for (int ns = 0; ns < 4; ++ns) {
            int nl = ns * 16 + l15;
            float4 val;
            val.x = acc[m][ns][0] + bias[m][0];
            val.y = acc[m][ns][1] + bias[m][1];
            val.z = acc[m][ns][2] + bias[m][2];
            val.w = acc[m][ns][3] + bias[m][3];
            *reinterpret_cast<float4*>(s_yf + nl * 136 + co0 + m * 16 + l4 * 4) = val;
        }
    __syncthreads();
#pragma unroll
    for (int it = 0; it < 8; ++it) {
        int flat = it * 256 + tid;
        int nl = flat >> 5, cq = flat & 31;
        float4 v = *reinterpret_cast<const float4*>(s_yf + nl * 136 + cq * 4);
        *reinterpret_cast<float4*>(accf + ((long long)(b * NTV + n0 + nl)) * 128 + cq * 4) = v;
    }
}

// ---------------- final: out = gn3(relu(acc fp32)), transpose to [b][c][n] fp32 ----------------
__global__ __launch_bounds__(256) void final_kernel(const float* __restrict__ accf,
                                                    const float* __restrict__ stats3,
                                                    const float* __restrict__ ng,
                                                    const float* __restrict__ nb,
                                                    float* __restrict__ out) {
    __shared__ float s_o[128 * 72];
    __shared__ float s_sc[128], s_bc[128];
    int tile = blockIdx.x, b = blockIdx.y, tid = threadIdx.x;
    int n0 = tile * 64;
    if (tid < 128) {
        int g = tid >> 4;
        float mu = stats3[b * 8 + g], rs = stats3[256 + b * 8 + g];
        float sv = rs * ng[tid];
        s_sc[tid] = sv;
        s_bc[tid] = nb[tid] - mu * sv;
    }
    __syncthreads();
#pragma unroll
    for (int it = 0; it < 8; ++it) {
        int flat = it * 256 + tid;
        int r = flat >> 5, cq = flat & 31;
        float4 v = *reinterpret_cast<const float4*>(accf + ((long long)(b * NTV + n0 + r)) * 128 + cq * 4);
        float f[4] = {v.x, v.y, v.z, v.w};
#pragma unroll
        for (int p = 0; p < 4; ++p) {
            int ci = cq * 4 + p;
            s_o[ci * 72 + r] = fmaxf(f[p], 0.f) * s_sc[ci] + s_bc[ci];
        }
    }
    __syncthreads();
#pragma unroll
    for (int it = 0; it < 8; ++it) {
        int flat = it * 256 + tid;
        int ci = flat >> 4, q = flat & 15;
        float4 v = *reinterpret_cast<const float4*>(s_o + ci * 72 + q * 4);
        *reinterpret_cast<float4*>(out + ((long long)(b * 128 + ci)) * NTV + n0 + q * 4) = v;
    }
}

extern "C" void kernel_launch(void* const* d_in, const int* in_sizes, int n_in,
                              void* d_out, int out_size, void* d_ws, size_t ws_size,
                              hipStream_t stream) {
    const float* x      = (const float*)d_in[0];
    const float* adj    = (const float*)d_in[1];
    const float* w_gat  = (const float*)d_in[2];
    const float* a_gat  = (const float*)d_in[3];
    const float* fus_w  = (const float*)d_in[4];
    const float* fus_b  = (const float*)d_in[5];
    const float* res_w  = (const float*)d_in[6];
    const float* res_b  = (const float*)d_in[7];
    const float* norm_g = (const float*)d_in[8];
    const float* norm_b = (const float*)d_in[9];
    const float* tg1[3], *tb1[3], *tw[3], *tbb[3], *tg2[3], *tb2[3];
    for (int i = 0; i < 3; i++) {
        tg1[i] = (const float*)d_in[10 + 6 * i + 0];
        tb1[i] = (const float*)d_in[10 + 6 * i + 1];
        tw[i]  = (const float*)d_in[10 + 6 * i + 2];
        tbb[i] = (const float*)d_in[10 + 6 * i + 3];
        tg2[i] = (const float*)d_in[10 + 6 * i + 4];
        tb2[i] = (const float*)d_in[10 + 6 * i + 5];
    }

    float* ws = (float*)d_ws;
    float* accf  = ws + ACC_OFF;                    // fp32, aliases xgt/wrb/wgbl (dead by fuse)
    bf16* xgt    = (bf16*)(ws + XGT_OFF);
    bf16* wrb[3] = { (bf16*)(ws + WRB3_OFF), (bf16*)(ws + WRB5_OFF), (bf16*)(ws + WRB7_OFF) };
    bf16* wgbl   = (bf16*)(ws + WGB_OFF);
    bf16* yb[3]  = { (bf16*)(ws + Y0_OFF), (bf16*)(ws + Y1_OFF), (bf16*)(ws + Y2_OFF) };
    bf16* xt     = (bf16*)(ws + XT_OFF);
    bf16* Abig   = (bf16*)(ws + ABIG_OFF);
    float* biasb = ws + BIAS_OFF;
    float* S1    = ws + STATS_OFF;
    float* S2    = S1 + 512;      // 3 consecutive buffers
    float* S3    = S1 + 2048;

    const int Ks[3] = { 3, 5, 7 };

    zero_stats_kernel<<<1, 256, 0, stream>>>(S1);
    for (int i = 0; i < 3; i++) {
        int tot = 128 * 128 * Ks[i];
        repack_wbf16_kernel<<<(tot + 255) / 256, 256, 0, stream>>>(tw[i], wrb[i], Ks[i]);
    }
    repack_wgbl_kernel<<<32, 256, 0, stream>>>(w_gat, wgbl);

    dim3 g64(100, 32), g128(50, 32), gstat(32, 16), ggat(256, 32);

    xt_kernel<<<g64, 256, 0, stream>>>(x, xt);

    // fused GAT: Wh MFMA + e via shfl + softmax + PV, one (b,t) per block
    gat_fused_kernel<<<ggat, 256, 0, stream>>>(xt, wgbl, adj, a_gat, xgt);

    stats_c128_kernel<false><<<gstat, 256, 0, stream>>>(xgt, S1);
    finalize_kernel<<<1, 256, 0, stream>>>(S1);

    conv_mfma_kernel<3><<<g128, 256, 0, stream>>>(xgt, wrb[0], tbb[0], tg1[0], tb1[0], S1, yb[0]);
    conv_mfma_kernel<5><<<g128, 256, 0, stream>>>(xgt, wrb[1], tbb[1], tg1[1], tb1[1], S1, yb[1]);
    conv_mfma_kernel<7><<<g128, 256, 0, stream>>>(xgt, wrb[2], tbb[2], tg1[2], tb1[2], S1, yb[2]);

    stats_c128_kernel<false><<<gstat, 256, 0, stream>>>(yb[0], S2);
    stats_c128_kernel<false><<<gstat, 256, 0, stream>>>(yb[1], S2 + 512);
    stats_c128_kernel<false><<<gstat, 256, 0, stream>>>(yb[2], S2 + 1024);
    finalize_kernel<<<3, 256, 0, stream>>>(S2);

    fold_kernel<<<dim3(32, 8), 256, 0, stream>>>(fus_w, fus_b, res_w, res_b,
                                                 tg2[0], tb2[0], tg2[1], tb2[1], tg2[2], tb2[2],
                                                 S2, S2 + 512, S2 + 1024, Abig, biasb);

    // fuse overwrites the xgt/wrb/wgbl region with fp32 acc (those are dead now)
    fuse_mfma_kernel<<<g64, 256, 0, stream>>>(yb[0], yb[1], yb[2], xt, Abig, biasb, accf);

    stats_f32_relu_kernel<<<gstat, 256, 0, stream>>>(accf, S3);
    finalize_kernel<<<1, 256, 0, stream>>>(S3);

    final_kernel<<<g64, 256, 0, stream>>>(accf, S3, norm_g, norm_b, (float*)d_out);
}